// Round 8
// baseline (776.480 us; speedup 1.0000x reference)
//
#include <hip/hip_runtime.h>
#include <math.h>

#define BB 128
#define SS 512
#define EE 300
#define HH 150
#define TN 16
#define LST 152  // tail LDS row stride (floats)
#define GS 752   // tail gate buffer row stride
#define UST 752  // transposed UL/UR row stride (cols 750..751 zero)

// ---- workspace byte offsets ----
#define OB_B1   0u            // conv B frags: 830 tiles * 2048 B
#define OB_B2   1699840u      // leaf-proj B frags: 200 tiles
#define OB_B3   2109440u      // leaf-gate B frags: 150 tiles
#define OB_UT   2416640u      // tree U frags: 500 tiles * 2048 B
#define OB_BC   3440640u      // bcat: 304 floats
#define OB_ULT  3442176u      // 150*752 floats (fp32, for k_tail)
#define OB_URT  3893376u
// h stored as split-bf16 planes, rows padded to 160 (cols 150..159 zero)
#define OB_HS0H 4344576u      // 128*512*160 ushorts
#define OB_HS0L 25316096u
#define OB_C0   46287616u     // fp32 128*512*150
#define OB_HS1H 85609216u     // 128*256*160 ushorts
#define OB_HS1L 96094976u
#define OB_C1   106580736u    // fp32 128*256*150

// LDS strides (ushorts)
#define EST 328
#define CST 328
#define LSU 168

typedef short s16x8 __attribute__((ext_vector_type(8)));
typedef float f32x4 __attribute__((ext_vector_type(4)));
#define MFMA __builtin_amdgcn_mfma_f32_16x16x32_bf16

typedef unsigned short ushort_t;
typedef unsigned int uint_t;

__device__ __forceinline__ float sigmoidf_(float x) {
    return 1.0f / (1.0f + __expf(-x));
}
__device__ __forceinline__ float tanh_fast(float x) {
    x = fminf(fmaxf(x, -15.0f), 15.0f);
    float e = __expf(2.0f * x);
    return (e - 1.0f) / (e + 1.0f);
}
__device__ __forceinline__ float bf2f(ushort_t u) {
    return __uint_as_float(((uint_t)u) << 16);
}
// split fp32 -> bf16 hi + bf16 lo (RNE both)
__device__ __forceinline__ void split_bf16(float f, ushort_t& hi, ushort_t& lo) {
    uint_t u = __float_as_uint(f);
    uint_t r = (u + 0x7fffu + ((u >> 16) & 1u)) >> 16;
    hi = (ushort_t)r;
    float d = f - __uint_as_float(r << 16);
    uint_t u2 = __float_as_uint(d);
    uint_t r2 = (u2 + 0x7fffu + ((u2 >> 16) & 1u)) >> 16;
    lo = (ushort_t)r2;
}

// conv B1 tile index: nt<12 -> kts 10..49 (40), nt>=12 -> kts 0..49 (50)
__device__ __forceinline__ int b1_tile(int nt, int kt) {
    return (nt < 12) ? nt * 40 + (kt - 10) : 480 + (nt - 12) * 50 + kt;
}

__device__ __forceinline__ void pack_frag(uint_t* out, const ushort_t* hv, const ushort_t* lv) {
    out[0] = hv[0] | (hv[1] << 16); out[1] = hv[2] | (hv[3] << 16);
    out[2] = hv[4] | (hv[5] << 16); out[3] = hv[6] | (hv[7] << 16);
    out[4] = lv[0] | (lv[1] << 16); out[5] = lv[2] | (lv[3] << 16);
    out[6] = lv[4] | (lv[5] << 16); out[7] = lv[6] | (lv[7] << 16);
}

// ---------------- k_prep (unchanged) ----------------
__global__ __launch_bounds__(256) void k_prep(
    const float* __restrict__ w3, const float* __restrict__ b3,
    const float* __restrict__ w4, const float* __restrict__ b4,
    const float* __restrict__ w5, const float* __restrict__ b5,
    const float* __restrict__ Wp, const float* __restrict__ Wx,
    const float* __restrict__ UL, const float* __restrict__ UR,
    char* __restrict__ wsb)
{
    const int W1 = 830 * 64, W2 = 200 * 64, W3 = 150 * 64, WU = 500 * 64;
    int i = blockIdx.x * 256 + threadIdx.x;
    if (i < W1) {
        int T = i >> 6, lane = i & 63;
        int nt, kt;
        if (T < 480) { nt = T / 40; kt = T % 40 + 10; }
        else { int T2 = T - 480; nt = 12 + T2 / 50; kt = T2 % 50; }
        int t = kt / 10, jjb = (kt - t * 10) * 32 + ((lane >> 4) << 3);
        int f = nt * 16 + (lane & 15);
        ushort_t hv[8], lv[8];
        #pragma unroll
        for (int e = 0; e < 8; ++e) {
            int jj = jjb + e;
            float w = 0.0f;
            if (f < 300 && jj < 300) {
                if (f < 100)      { if (t >= 1 && t <= 3) w = w3[f * 900 + jj * 3 + (t - 1)]; }
                else if (f < 200) { if (t >= 1)           w = w4[(f - 100) * 1200 + jj * 4 + (t - 1)]; }
                else              {                       w = w5[(f - 200) * 1500 + jj * 5 + t]; }
            }
            split_bf16(w, hv[e], lv[e]);
        }
        pack_frag((uint_t*)(wsb + OB_B1 + ((size_t)T * 64 + lane) * 32), hv, lv);
        return;
    }
    i -= W1;
    if (i < W2) {
        int T = i >> 6, lane = i & 63;
        int nt = T / 20, kt = T % 20;
        int h = nt * 16 + (lane & 15);
        int kb = kt * 32 + ((lane >> 4) << 3);
        ushort_t hv[8], lv[8];
        #pragma unroll
        for (int e = 0; e < 8; ++e) {
            int k = kb + e;
            float w = 0.0f;
            if (h < 150) {
                if (kt < 10) { if (k < 300) w = Wp[h * 600 + k]; }
                else { int k2 = k - 320; if (k2 < 300) w = Wp[h * 600 + 300 + k2]; }
            }
            split_bf16(w, hv[e], lv[e]);
        }
        pack_frag((uint_t*)(wsb + OB_B2 + ((size_t)T * 64 + lane) * 32), hv, lv);
        return;
    }
    i -= W2;
    if (i < W3) {
        int T = i >> 6, lane = i & 63;
        int nt3 = T / 5, kt = T % 5;
        int g = nt3 / 10, h16 = nt3 % 10;
        int h = h16 * 16 + (lane & 15);
        int kb = kt * 32 + ((lane >> 4) << 3);
        int row = (g == 0 ? 0 : (g == 1 ? 450 : 600)) + h;
        ushort_t hv[8], lv[8];
        #pragma unroll
        for (int e = 0; e < 8; ++e) {
            int k = kb + e;
            float w = (h < 150 && k < 150) ? Wx[row * 150 + k] : 0.0f;
            split_bf16(w, hv[e], lv[e]);
        }
        pack_frag((uint_t*)(wsb + OB_B3 + ((size_t)T * 64 + lane) * 32), hv, lv);
        return;
    }
    i -= W3;
    if (i < WU) {
        int T = i >> 6, lane = i & 63;
        int g = T / 100, rem = T - g * 100;
        int ht = rem / 10, kt = rem - ht * 10;
        int h = ht * 16 + (lane & 15);
        int kb = kt * 32 + ((lane >> 4) << 3);
        ushort_t hv[8], lv[8];
        #pragma unroll
        for (int e = 0; e < 8; ++e) {
            int k = kb + e;
            int half = (k >= 160);
            int j = k - half * 160;
            float w = 0.0f;
            if (h < 150 && j < 150) {
                const float* U = half ? UR : UL;
                w = U[(g * 150 + h) * 150 + j];
            }
            split_bf16(w, hv[e], lv[e]);
        }
        pack_frag((uint_t*)(wsb + OB_UT + ((size_t)T * 64 + lane) * 32), hv, lv);
        return;
    }
    i -= WU;
    if (i < 304) {
        float v = (i < 100) ? b3[i] : (i < 200 ? b4[i - 100] : (i < 300 ? b5[i - 200] : 0.0f));
        ((float*)(wsb + OB_BC))[i] = v;
        return;
    }
    i -= 304;
    if (i < 150 * UST) {
        int j = i / UST, o = i - j * UST;
        ((float*)(wsb + OB_ULT))[i] = (o < 750) ? UL[o * 150 + j] : 0.0f;
        return;
    }
    i -= 150 * UST;
    if (i < 150 * UST) {
        int j = i / UST, o = i - j * UST;
        ((float*)(wsb + OB_URT))[i] = (o < 750) ? UR[o * 150 + j] : 0.0f;
        return;
    }
}

// ---------------- k_leaf: R7 pipelined version; epilogue writes split-bf16 h ----
__global__ __launch_bounds__(640) void k_leaf(
    const int* __restrict__ x, const float* __restrict__ emb,
    const ushort_t* __restrict__ b1f, const ushort_t* __restrict__ b2f,
    const ushort_t* __restrict__ b3f, const float* __restrict__ bcat,
    const float* __restrict__ bp, const float* __restrict__ bx,
    ushort_t* __restrict__ hsh, ushort_t* __restrict__ hsl,
    float* __restrict__ c0)
{
    __shared__ ushort_t ehi[36 * EST], elo[36 * EST];
    __shared__ ushort_t chi[32 * CST], clo[32 * CST];
    __shared__ ushort_t lhi[32 * LSU], llo[32 * LSU];

    const int b   = blockIdx.x;
    const int s0  = blockIdx.y * 32;
    const int tid = threadIdx.x;
    const int wv  = tid >> 6;
    const int lane = tid & 63;
    const int lc = lane & 15, lq = lane >> 4;

    // ---- phase 0: gather e rows (36 x 300), split to bf16 hi/lo ----
    for (int idx = tid; idx < 36 * 75; idx += 640) {
        int r = idx / 75, q = idx - r * 75;
        int sp = s0 - 2 + r;
        float4 v = make_float4(0.f, 0.f, 0.f, 0.f);
        if (sp >= 0 && sp < SS) {
            int tok = x[b * SS + sp];
            v = *reinterpret_cast<const float4*>(emb + (size_t)tok * EE + q * 4);
        }
        ushort_t h4[4], l4[4];
        split_bf16(v.x, h4[0], l4[0]); split_bf16(v.y, h4[1], l4[1]);
        split_bf16(v.z, h4[2], l4[2]); split_bf16(v.w, h4[3], l4[3]);
        *(ushort4*)&ehi[r * EST + q * 4] = make_ushort4(h4[0], h4[1], h4[2], h4[3]);
        *(ushort4*)&elo[r * EST + q * 4] = make_ushort4(l4[0], l4[1], l4[2], l4[3]);
    }
    for (int idx = tid; idx < 36 * 20; idx += 640) {
        int r = idx / 20, c = 300 + idx % 20;
        ehi[r * EST + c] = 0; elo[r * EST + c] = 0;
    }
    for (int idx = tid; idx < 32 * 16; idx += 640) {
        int r = idx / 16, c = 304 + idx % 16;
        chi[r * CST + c] = 0; clo[r * CST + c] = 0;
    }
    __syncthreads();

    // ---- phase 1: conv GEMM, 2-slot B double-buffer ----
    {
        const int nt0 = wv;
        const int nt1 = (wv == 9) ? 18 : wv + 10;
        const bool st1 = (wv < 9);
        const int f0 = nt0 * 16 + lc;
        const int f1 = nt1 * 16 + lc;
        const float bv0 = bcat[f0];
        const float bv1 = st1 ? bcat[f1] : 0.0f;
        f32x4 c00 = {bv0, bv0, bv0, bv0}, c01 = c00;
        f32x4 c10 = {bv1, bv1, bv1, bv1}, c11 = c10;

        if (nt1 >= 12) {
            #pragma unroll
            for (int kt = 0; kt < 10; ++kt) {
                const ushort_t* p8 = b1f + ((size_t)b1_tile(nt1, kt) * 64 + lane) * 16;
                s16x8 Bh = *(const s16x8*)p8;
                s16x8 Bl = *(const s16x8*)(p8 + 8);
                int jj = kt * 32 + (lq << 3);
                s16x8 A0h = *(const s16x8*)&ehi[lc * EST + jj];
                s16x8 A0l = *(const s16x8*)&elo[lc * EST + jj];
                s16x8 A1h = *(const s16x8*)&ehi[(lc + 16) * EST + jj];
                s16x8 A1l = *(const s16x8*)&elo[(lc + 16) * EST + jj];
                c10 = MFMA(A0h, Bh, c10, 0, 0, 0); c10 = MFMA(A0h, Bl, c10, 0, 0, 0); c10 = MFMA(A0l, Bh, c10, 0, 0, 0);
                c11 = MFMA(A1h, Bh, c11, 0, 0, 0); c11 = MFMA(A1h, Bl, c11, 0, 0, 0); c11 = MFMA(A1l, Bh, c11, 0, 0, 0);
            }
        }

        const ushort_t* p;
        p = b1f + ((size_t)b1_tile(nt0, 10) * 64 + lane) * 16;
        s16x8 Bha0 = *(const s16x8*)p, Bla0 = *(const s16x8*)(p + 8);
        p = b1f + ((size_t)b1_tile(nt1, 10) * 64 + lane) * 16;
        s16x8 Bha1 = *(const s16x8*)p, Bla1 = *(const s16x8*)(p + 8);
        p = b1f + ((size_t)b1_tile(nt0, 11) * 64 + lane) * 16;
        s16x8 Bhb0 = *(const s16x8*)p, Blb0 = *(const s16x8*)(p + 8);
        p = b1f + ((size_t)b1_tile(nt1, 11) * 64 + lane) * 16;
        s16x8 Bhb1 = *(const s16x8*)p, Blb1 = *(const s16x8*)(p + 8);

        for (int kt = 10; kt < 50; kt += 2) {
            int k2 = (kt + 2 < 50) ? kt + 2 : 10;
            p = b1f + ((size_t)b1_tile(nt0, k2) * 64 + lane) * 16;
            s16x8 nha0 = *(const s16x8*)p, nla0 = *(const s16x8*)(p + 8);
            p = b1f + ((size_t)b1_tile(nt1, k2) * 64 + lane) * 16;
            s16x8 nha1 = *(const s16x8*)p, nla1 = *(const s16x8*)(p + 8);
            {
                int t = kt / 10;
                int jj = (kt - t * 10) * 32 + (lq << 3);
                int ra = lc + t;
                s16x8 A0h = *(const s16x8*)&ehi[ra * EST + jj];
                s16x8 A0l = *(const s16x8*)&elo[ra * EST + jj];
                s16x8 A1h = *(const s16x8*)&ehi[(ra + 16) * EST + jj];
                s16x8 A1l = *(const s16x8*)&elo[(ra + 16) * EST + jj];
                c00 = MFMA(A0h, Bha0, c00, 0, 0, 0); c00 = MFMA(A0h, Bla0, c00, 0, 0, 0); c00 = MFMA(A0l, Bha0, c00, 0, 0, 0);
                c01 = MFMA(A1h, Bha0, c01, 0, 0, 0); c01 = MFMA(A1h, Bla0, c01, 0, 0, 0); c01 = MFMA(A1l, Bha0, c01, 0, 0, 0);
                c10 = MFMA(A0h, Bha1, c10, 0, 0, 0); c10 = MFMA(A0h, Bla1, c10, 0, 0, 0); c10 = MFMA(A0l, Bha1, c10, 0, 0, 0);
                c11 = MFMA(A1h, Bha1, c11, 0, 0, 0); c11 = MFMA(A1h, Bla1, c11, 0, 0, 0); c11 = MFMA(A1l, Bha1, c11, 0, 0, 0);
            }
            int k3 = (kt + 3 < 50) ? kt + 3 : 10;
            p = b1f + ((size_t)b1_tile(nt0, k3) * 64 + lane) * 16;
            s16x8 nhb0 = *(const s16x8*)p, nlb0 = *(const s16x8*)(p + 8);
            p = b1f + ((size_t)b1_tile(nt1, k3) * 64 + lane) * 16;
            s16x8 nhb1 = *(const s16x8*)p, nlb1 = *(const s16x8*)(p + 8);
            {
                int kb2 = kt + 1;
                int t = kb2 / 10;
                int jj = (kb2 - t * 10) * 32 + (lq << 3);
                int ra = lc + t;
                s16x8 A0h = *(const s16x8*)&ehi[ra * EST + jj];
                s16x8 A0l = *(const s16x8*)&elo[ra * EST + jj];
                s16x8 A1h = *(const s16x8*)&ehi[(ra + 16) * EST + jj];
                s16x8 A1l = *(const s16x8*)&elo[(ra + 16) * EST + jj];
                c00 = MFMA(A0h, Bhb0, c00, 0, 0, 0); c00 = MFMA(A0h, Blb0, c00, 0, 0, 0); c00 = MFMA(A0l, Bhb0, c00, 0, 0, 0);
                c01 = MFMA(A1h, Bhb0, c01, 0, 0, 0); c01 = MFMA(A1h, Blb0, c01, 0, 0, 0); c01 = MFMA(A1l, Bhb0, c01, 0, 0, 0);
                c10 = MFMA(A0h, Bhb1, c10, 0, 0, 0); c10 = MFMA(A0h, Blb1, c10, 0, 0, 0); c10 = MFMA(A0l, Bhb1, c10, 0, 0, 0);
                c11 = MFMA(A1h, Bhb1, c11, 0, 0, 0); c11 = MFMA(A1h, Blb1, c11, 0, 0, 0); c11 = MFMA(A1l, Bhb1, c11, 0, 0, 0);
            }
            Bha0 = nha0; Bla0 = nla0; Bha1 = nha1; Bla1 = nla1;
            Bhb0 = nhb0; Blb0 = nlb0; Bhb1 = nhb1; Blb1 = nlb1;
        }

        #pragma unroll
        for (int r = 0; r < 4; ++r) {
            int pp = lq * 4 + r;
            ushort_t hu, lu;
            split_bf16(fmaxf(c00[r], 0.0f), hu, lu);
            chi[pp * CST + f0] = hu; clo[pp * CST + f0] = lu;
            split_bf16(fmaxf(c01[r], 0.0f), hu, lu);
            chi[(pp + 16) * CST + f0] = hu; clo[(pp + 16) * CST + f0] = lu;
            if (st1) {
                split_bf16(fmaxf(c10[r], 0.0f), hu, lu);
                chi[pp * CST + f1] = hu; clo[pp * CST + f1] = lu;
                split_bf16(fmaxf(c11[r], 0.0f), hu, lu);
                chi[(pp + 16) * CST + f1] = hu; clo[(pp + 16) * CST + f1] = lu;
            }
        }
    }
    __syncthreads();

    // ---- phase 2: leaf projection GEMM ----
    {
        const int hcol = wv * 16 + lc;
        const float bv = (hcol < 150) ? bp[hcol] : 0.0f;
        f32x4 d0 = {bv, bv, bv, bv}, d1 = d0;
        #pragma unroll
        for (int kt = 0; kt < 20; ++kt) {
            s16x8 A0h, A0l, A1h, A1l;
            if (kt < 10) {
                int col = kt * 32 + (lq << 3);
                int ra = lc + 2;
                A0h = *(const s16x8*)&ehi[ra * EST + col];
                A0l = *(const s16x8*)&elo[ra * EST + col];
                A1h = *(const s16x8*)&ehi[(ra + 16) * EST + col];
                A1l = *(const s16x8*)&elo[(ra + 16) * EST + col];
            } else {
                int col = (kt - 10) * 32 + (lq << 3);
                A0h = *(const s16x8*)&chi[lc * CST + col];
                A0l = *(const s16x8*)&clo[lc * CST + col];
                A1h = *(const s16x8*)&chi[(lc + 16) * CST + col];
                A1l = *(const s16x8*)&clo[(lc + 16) * CST + col];
            }
            const ushort_t* p8 = b2f + ((size_t)(wv * 20 + kt) * 64 + lane) * 16;
            s16x8 Bh = *(const s16x8*)p8;
            s16x8 Bl = *(const s16x8*)(p8 + 8);
            d0 = MFMA(A0h, Bh, d0, 0, 0, 0);
            d0 = MFMA(A0h, Bl, d0, 0, 0, 0);
            d0 = MFMA(A0l, Bh, d0, 0, 0, 0);
            d1 = MFMA(A1h, Bh, d1, 0, 0, 0);
            d1 = MFMA(A1h, Bl, d1, 0, 0, 0);
            d1 = MFMA(A1l, Bh, d1, 0, 0, 0);
        }
        #pragma unroll
        for (int r = 0; r < 4; ++r) {
            int pp = lq * 4 + r;
            ushort_t hu, lu;
            split_bf16(d0[r], hu, lu);
            lhi[pp * LSU + hcol] = hu; llo[pp * LSU + hcol] = lu;
            split_bf16(d1[r], hu, lu);
            lhi[(pp + 16) * LSU + hcol] = hu; llo[(pp + 16) * LSU + hcol] = lu;
        }
    }
    __syncthreads();

    // ---- phase 3: leaf gates (i,o,u) GEMM + cell; write split-bf16 h + fp32 c ----
    {
        const int hc = wv * 16 + lc;
        const bool hval = (hc < 150);
        const float bi = hval ? bx[hc] : 0.0f;
        const float bo = hval ? bx[450 + hc] : 0.0f;
        const float bu = hval ? bx[600 + hc] : 0.0f;
        f32x4 gi0 = {bi, bi, bi, bi}, gi1 = gi0;
        f32x4 go0 = {bo, bo, bo, bo}, go1 = go0;
        f32x4 gu0 = {bu, bu, bu, bu}, gu1 = gu0;
        #pragma unroll
        for (int kt = 0; kt < 5; ++kt) {
            int col = kt * 32 + (lq << 3);
            s16x8 A0h = *(const s16x8*)&lhi[lc * LSU + col];
            s16x8 A0l = *(const s16x8*)&llo[lc * LSU + col];
            s16x8 A1h = *(const s16x8*)&lhi[(lc + 16) * LSU + col];
            s16x8 A1l = *(const s16x8*)&llo[(lc + 16) * LSU + col];
            const ushort_t* p8i = b3f + ((size_t)((0 + wv) * 5 + kt) * 64 + lane) * 16;
            const ushort_t* p8o = b3f + ((size_t)((10 + wv) * 5 + kt) * 64 + lane) * 16;
            const ushort_t* p8u = b3f + ((size_t)((20 + wv) * 5 + kt) * 64 + lane) * 16;
            s16x8 Bh, Bl;
            Bh = *(const s16x8*)p8i; Bl = *(const s16x8*)(p8i + 8);
            gi0 = MFMA(A0h, Bh, gi0, 0, 0, 0); gi0 = MFMA(A0h, Bl, gi0, 0, 0, 0); gi0 = MFMA(A0l, Bh, gi0, 0, 0, 0);
            gi1 = MFMA(A1h, Bh, gi1, 0, 0, 0); gi1 = MFMA(A1h, Bl, gi1, 0, 0, 0); gi1 = MFMA(A1l, Bh, gi1, 0, 0, 0);
            Bh = *(const s16x8*)p8o; Bl = *(const s16x8*)(p8o + 8);
            go0 = MFMA(A0h, Bh, go0, 0, 0, 0); go0 = MFMA(A0h, Bl, go0, 0, 0, 0); go0 = MFMA(A0l, Bh, go0, 0, 0, 0);
            go1 = MFMA(A1h, Bh, go1, 0, 0, 0); go1 = MFMA(A1h, Bl, go1, 0, 0, 0); go1 = MFMA(A1l, Bh, go1, 0, 0, 0);
            Bh = *(const s16x8*)p8u; Bl = *(const s16x8*)(p8u + 8);
            gu0 = MFMA(A0h, Bh, gu0, 0, 0, 0); gu0 = MFMA(A0h, Bl, gu0, 0, 0, 0); gu0 = MFMA(A0l, Bh, gu0, 0, 0, 0);
            gu1 = MFMA(A1h, Bh, gu1, 0, 0, 0); gu1 = MFMA(A1h, Bl, gu1, 0, 0, 0); gu1 = MFMA(A1l, Bh, gu1, 0, 0, 0);
        }
        #pragma unroll
        for (int r = 0; r < 4; ++r) {
            {
                int s = s0 + lq * 4 + r;
                size_t row = (size_t)b * SS + s;
                if (hval) {
                    float iv = sigmoidf_(gi0[r]), ov = sigmoidf_(go0[r]), uv = tanh_fast(gu0[r]);
                    float cc = iv * uv;
                    float hh = ov * tanh_fast(cc);
                    c0[row * HH + hc] = cc;
                    ushort_t hu, lu; split_bf16(hh, hu, lu);
                    hsh[row * 160 + hc] = hu; hsl[row * 160 + hc] = lu;
                } else {
                    hsh[row * 160 + hc] = 0; hsl[row * 160 + hc] = 0;
                }
            }
            {
                int s = s0 + 16 + lq * 4 + r;
                size_t row = (size_t)b * SS + s;
                if (hval) {
                    float iv = sigmoidf_(gi1[r]), ov = sigmoidf_(go1[r]), uv = tanh_fast(gu1[r]);
                    float cc = iv * uv;
                    float hh = ov * tanh_fast(cc);
                    c0[row * HH + hc] = cc;
                    ushort_t hu, lu; split_bf16(hh, hu, lu);
                    hsh[row * 160 + hc] = hu; hsl[row * 160 + hc] = lu;
                } else {
                    hsh[row * 160 + hc] = 0; hsl[row * 160 + hc] = 0;
                }
            }
        }
    }
}

// ---------------- k_tree2: zero-LDS MFMA tree level; 320 thr = 5 waves -------
// grid: (BB, (n_out/32)*2); y&1 selects h-tile group (0..4 / 5..9), y>>1 = node group.
// A-fragments load per-lane from split-bf16 h in global (rows padded to 160; children
// 2m/2m+1 contiguous so logical k=0..319 is linear).
__global__ __launch_bounds__(320) void k_tree2(
    const ushort_t* __restrict__ ih, const ushort_t* __restrict__ il,
    const float* __restrict__ in_c,
    ushort_t* __restrict__ oh, ushort_t* __restrict__ ol,
    float* __restrict__ out_c,
    int n_out,
    const ushort_t* __restrict__ utf, const float* __restrict__ bx)
{
    const int b    = blockIdx.x;
    const int y    = blockIdx.y;
    const int hgrp = y & 1;
    const int m0   = (y >> 1) * 32;
    const int tid  = threadIdx.x;
    const int wv   = tid >> 6, lane = tid & 63;
    const int lc   = lane & 15, lq = lane >> 4;
    const int ht   = hgrp * 5 + wv;
    const int n_in = n_out * 2;

    const size_t abase = ((size_t)b * n_in + 2 * m0) * 160 + (size_t)lc * 320 + (lq << 3);
    const ushort_t* pah = ih + abase;
    const ushort_t* pal = il + abase;

    const int hc = ht * 16 + lc;
    const bool hval = (hc < 150);
    const float bi = hval ? bx[hc] : 0.f;
    const float bl = hval ? bx[150 + hc] : 0.f;
    const float br = hval ? bx[300 + hc] : 0.f;
    const float bo = hval ? bx[450 + hc] : 0.f;
    const float bu = hval ? bx[600 + hc] : 0.f;
    f32x4 ai0 = {bi, bi, bi, bi}, ai1 = ai0;
    f32x4 al0 = {bl, bl, bl, bl}, al1 = al0;
    f32x4 ar0 = {br, br, br, br}, ar1 = ar0;
    f32x4 ao0 = {bo, bo, bo, bo}, ao1 = ao0;
    f32x4 au0 = {bu, bu, bu, bu}, au1 = au0;

    const size_t gstride = (size_t)100 * 1024;   // 100 tiles * 1024 ushorts
    for (int kt = 0; kt < 10; ++kt) {
        int off = kt * 32;
        s16x8 A0h = *(const s16x8*)(pah + off);
        s16x8 A0l = *(const s16x8*)(pal + off);
        s16x8 A1h = *(const s16x8*)(pah + 5120 + off);   // +16*320
        s16x8 A1l = *(const s16x8*)(pal + 5120 + off);
        const ushort_t* pb = utf + ((size_t)(ht * 10 + kt) * 64 + lane) * 16;
        s16x8 Bh, Bl;
        Bh = *(const s16x8*)pb; Bl = *(const s16x8*)(pb + 8);
        ai0 = MFMA(A0h, Bh, ai0, 0, 0, 0); ai0 = MFMA(A0h, Bl, ai0, 0, 0, 0); ai0 = MFMA(A0l, Bh, ai0, 0, 0, 0);
        ai1 = MFMA(A1h, Bh, ai1, 0, 0, 0); ai1 = MFMA(A1h, Bl, ai1, 0, 0, 0); ai1 = MFMA(A1l, Bh, ai1, 0, 0, 0);
        pb += gstride;
        Bh = *(const s16x8*)pb; Bl = *(const s16x8*)(pb + 8);
        al0 = MFMA(A0h, Bh, al0, 0, 0, 0); al0 = MFMA(A0h, Bl, al0, 0, 0, 0); al0 = MFMA(A0l, Bh, al0, 0, 0, 0);
        al1 = MFMA(A1h, Bh, al1, 0, 0, 0); al1 = MFMA(A1h, Bl, al1, 0, 0, 0); al1 = MFMA(A1l, Bh, al1, 0, 0, 0);
        pb += gstride;
        Bh = *(const s16x8*)pb; Bl = *(const s16x8*)(pb + 8);
        ar0 = MFMA(A0h, Bh, ar0, 0, 0, 0); ar0 = MFMA(A0h, Bl, ar0, 0, 0, 0); ar0 = MFMA(A0l, Bh, ar0, 0, 0, 0);
        ar1 = MFMA(A1h, Bh, ar1, 0, 0, 0); ar1 = MFMA(A1h, Bl, ar1, 0, 0, 0); ar1 = MFMA(A1l, Bh, ar1, 0, 0, 0);
        pb += gstride;
        Bh = *(const s16x8*)pb; Bl = *(const s16x8*)(pb + 8);
        ao0 = MFMA(A0h, Bh, ao0, 0, 0, 0); ao0 = MFMA(A0h, Bl, ao0, 0, 0, 0); ao0 = MFMA(A0l, Bh, ao0, 0, 0, 0);
        ao1 = MFMA(A1h, Bh, ao1, 0, 0, 0); ao1 = MFMA(A1h, Bl, ao1, 0, 0, 0); ao1 = MFMA(A1l, Bh, ao1, 0, 0, 0);
        pb += gstride;
        Bh = *(const s16x8*)pb; Bl = *(const s16x8*)(pb + 8);
        au0 = MFMA(A0h, Bh, au0, 0, 0, 0); au0 = MFMA(A0h, Bl, au0, 0, 0, 0); au0 = MFMA(A0l, Bh, au0, 0, 0, 0);
        au1 = MFMA(A1h, Bh, au1, 0, 0, 0); au1 = MFMA(A1h, Bl, au1, 0, 0, 0); au1 = MFMA(A1l, Bh, au1, 0, 0, 0);
    }

    #pragma unroll
    for (int r = 0; r < 4; ++r) {
        int ml = lq * 4 + r;
        {
            int m = m0 + ml;
            size_t hrow = (size_t)b * n_out + m;
            if (hval) {
                size_t cb = ((size_t)b * n_in + 2 * m) * HH + hc;
                float iv = sigmoidf_(ai0[r]);
                float fl = sigmoidf_(al0[r]);
                float fr = sigmoidf_(ar0[r]);
                float ov = sigmoidf_(ao0[r]);
                float uv = tanh_fast(au0[r]);
                float cc = iv * uv + fl * in_c[cb] + fr * in_c[cb + HH];
                out_c[hrow * HH + hc] = cc;
                float hh = ov * tanh_fast(cc);
                ushort_t hu, lu; split_bf16(hh, hu, lu);
                oh[hrow * 160 + hc] = hu; ol[hrow * 160 + hc] = lu;
            } else {
                oh[hrow * 160 + hc] = 0; ol[hrow * 160 + hc] = 0;
            }
        }
        {
            int m = m0 + 16 + ml;
            size_t hrow = (size_t)b * n_out + m;
            if (hval) {
                size_t cb = ((size_t)b * n_in + 2 * m) * HH + hc;
                float iv = sigmoidf_(ai1[r]);
                float fl = sigmoidf_(al1[r]);
                float fr = sigmoidf_(ar1[r]);
                float ov = sigmoidf_(ao1[r]);
                float uv = tanh_fast(au1[r]);
                float cc = iv * uv + fl * in_c[cb] + fr * in_c[cb + HH];
                out_c[hrow * HH + hc] = cc;
                float hh = ov * tanh_fast(cc);
                ushort_t hu, lu; split_bf16(hh, hu, lu);
                oh[hrow * 160 + hc] = hu; ol[hrow * 160 + hc] = lu;
            } else {
                oh[hrow * 160 + hc] = 0; ol[hrow * 160 + hc] = 0;
            }
        }
    }
}

// ---------------- k_tail: levels 16..1 in LDS + head MLP (fp32; h from split pair) ----
__global__ __launch_bounds__(384) void k_tail(
    const ushort_t* __restrict__ ih, const ushort_t* __restrict__ il,
    const float* __restrict__ in_c,
    const float* __restrict__ ULT, const float* __restrict__ URT,
    const float* __restrict__ bx,
    const float* __restrict__ W1, const float* __restrict__ b1,
    const float* __restrict__ W2, const float* __restrict__ b2,
    float* __restrict__ out)
{
    __shared__ float pool[96 * LST + TN * GS];
    float* Ah = pool;
    float* Ac = Ah + 32 * LST;
    float* Bh = Ac + 32 * LST;
    float* Bc = Bh + 16 * LST;
    float* gs = Bc + 16 * LST;
    __shared__ float z_s[80];

    const int b   = blockIdx.x;
    const int tid = threadIdx.x;

    for (int idx = tid; idx < 32 * HH; idx += 384) {
        int p = idx / HH, j = idx - p * HH;
        size_t hr = ((size_t)b * 32 + p) * 160 + j;
        Ah[p * LST + j] = bf2f(ih[hr]) + bf2f(il[hr]);
        Ac[p * LST + j] = in_c[((size_t)b * 32 + p) * HH + j];
    }

    const int o1 = tid, o2 = tid + 384;
    const int o2c = (o2 < 752) ? o2 : 751;
    const float bx1 = bx[o1];
    const float bx2 = (o2 < 750) ? bx[o2] : 0.0f;
    const float* ul1 = ULT + o1; const float* ur1 = URT + o1;
    const float* ul2 = ULT + o2c; const float* ur2 = URT + o2c;

    float* curh = Ah; float* curc = Ac;
    float* nxth = Bh; float* nxtc = Bc;

    for (int n = 16; n >= 1; n >>= 1) {
        __syncthreads();
        {
            float a1[TN], a2[TN];
            #pragma unroll
            for (int m = 0; m < TN; ++m) { a1[m] = bx1; a2[m] = bx2; }
            for (int j = 0; j < 150; j += 2) {
                int r0 = j * UST, r1 = (j + 1) * UST;
                float wl1a = ul1[r0], wl1b = ul1[r1];
                float wr1a = ur1[r0], wr1b = ur1[r1];
                float wl2a = ul2[r0], wl2b = ul2[r1];
                float wr2a = ur2[r0], wr2b = ur2[r1];
                #pragma unroll
                for (int m = 0; m < TN; ++m) {
                    float2 lv = *(const float2*)(curh + (2 * m) * LST + j);
                    float2 rv = *(const float2*)(curh + (2 * m + 1) * LST + j);
                    a1[m] += lv.x * wl1a + lv.y * wl1b + rv.x * wr1a + rv.y * wr1b;
                    a2[m] += lv.x * wl2a + lv.y * wl2b + rv.x * wr2a + rv.y * wr2b;
                }
            }
            #pragma unroll
            for (int m = 0; m < TN; ++m) {
                if (m < n) {
                    gs[m * GS + o1] = a1[m];
                    if (o2 < 750) gs[m * GS + o2] = a2[m];
                }
            }
        }
        __syncthreads();
        for (int idx = tid; idx < n * HH; idx += 384) {
            int m = idx / HH, h = idx - m * HH;
            float iv = sigmoidf_(gs[m * GS + h]);
            float fL = sigmoidf_(gs[m * GS + 150 + h]);
            float fR = sigmoidf_(gs[m * GS + 300 + h]);
            float ov = sigmoidf_(gs[m * GS + 450 + h]);
            float uv = tanh_fast(gs[m * GS + 600 + h]);
            float cc = iv * uv + fL * curc[2 * m * LST + h] + fR * curc[(2 * m + 1) * LST + h];
            nxth[m * LST + h] = ov * tanh_fast(cc);
            nxtc[m * LST + h] = cc;
        }
        float* t;
        t = curh; curh = nxth; nxth = t;
        t = curc; curc = nxtc; nxtc = t;
    }
    __syncthreads();

    if (tid < 75) {
        const float* w = W1 + (size_t)tid * 150;
        float acc = b1[tid];
        for (int j = 0; j < 150; ++j) acc += curh[j] * w[j];
        z_s[tid] = fmaxf(acc, 0.0f);
    }
    __syncthreads();
    if (tid < 3) {
        const float* w = W2 + (size_t)tid * 75;
        float acc = b2[tid];
        for (int j = 0; j < 75; ++j) acc += z_s[j] * w[j];
        out[(size_t)b * 3 + tid] = acc;
    }
}

extern "C" void kernel_launch(void* const* d_in, const int* in_sizes, int n_in,
                              void* d_out, int out_size, void* d_ws, size_t ws_size,
                              hipStream_t stream) {
    const int*   x   = (const int*)  d_in[0];
    const float* emb = (const float*)d_in[1];
    const float* w3  = (const float*)d_in[2];
    const float* b3  = (const float*)d_in[3];
    const float* w4  = (const float*)d_in[4];
    const float* b4  = (const float*)d_in[5];
    const float* w5  = (const float*)d_in[6];
    const float* b5  = (const float*)d_in[7];
    const float* Wp  = (const float*)d_in[8];
    const float* bp  = (const float*)d_in[9];
    const float* Wx  = (const float*)d_in[10];
    const float* bx  = (const float*)d_in[11];
    const float* UL  = (const float*)d_in[12];
    const float* UR  = (const float*)d_in[13];
    const float* W1  = (const float*)d_in[14];
    const float* b1  = (const float*)d_in[15];
    const float* W2  = (const float*)d_in[16];
    const float* b2  = (const float*)d_in[17];
    float* out = (float*)d_out;

    char* wsb = (char*)d_ws;
    const ushort_t* b1f = (const ushort_t*)(wsb + OB_B1);
    const ushort_t* b2f = (const ushort_t*)(wsb + OB_B2);
    const ushort_t* b3f = (const ushort_t*)(wsb + OB_B3);
    const ushort_t* utf = (const ushort_t*)(wsb + OB_UT);
    const float* bcat = (const float*)(wsb + OB_BC);
    const float* ULT  = (const float*)(wsb + OB_ULT);
    const float* URT  = (const float*)(wsb + OB_URT);
    ushort_t* hs0h = (ushort_t*)(wsb + OB_HS0H);
    ushort_t* hs0l = (ushort_t*)(wsb + OB_HS0L);
    float*    c0   = (float*)   (wsb + OB_C0);
    ushort_t* hs1h = (ushort_t*)(wsb + OB_HS1H);
    ushort_t* hs1l = (ushort_t*)(wsb + OB_HS1L);
    float*    c1   = (float*)   (wsb + OB_C1);

    {
        int total = 830 * 64 + 200 * 64 + 150 * 64 + 500 * 64 + 304 + 2 * 150 * UST;
        k_prep<<<(total + 255) / 256, 256, 0, stream>>>(
            w3, b3, w4, b4, w5, b5, Wp, Wx, UL, UR, wsb);
    }

    k_leaf<<<dim3(BB, SS / 32), 640, 0, stream>>>(
        x, emb, b1f, b2f, b3f, bcat, bp, bx, hs0h, hs0l, c0);

    k_tree2<<<dim3(BB, 16), 320, 0, stream>>>(hs0h, hs0l, c0, hs1h, hs1l, c1, 256, utf, bx);
    k_tree2<<<dim3(BB,  8), 320, 0, stream>>>(hs1h, hs1l, c1, hs0h, hs0l, c0, 128, utf, bx);
    k_tree2<<<dim3(BB,  4), 320, 0, stream>>>(hs0h, hs0l, c0, hs1h, hs1l, c1,  64, utf, bx);
    k_tree2<<<dim3(BB,  2), 320, 0, stream>>>(hs1h, hs1l, c1, hs0h, hs0l, c0,  32, utf, bx);

    k_tail<<<BB, 384, 0, stream>>>(hs0h, hs0l, c0, ULT, URT, bx, W1, b1, W2, b2, out);
}

// Round 9
// 745.248 us; speedup vs baseline: 1.0419x; 1.0419x over previous
//
#include <hip/hip_runtime.h>
#include <math.h>

#define BB 128
#define SS 512
#define EE 300
#define HH 150
#define TN 16
#define LST 152  // tail LDS row stride (floats)
#define GS 752   // tail gate buffer row stride
#define UST 752  // transposed UL/UR row stride (cols 750..751 zero)

// ---- workspace byte offsets ----
#define OB_B1   0u            // conv B frags: 830 tiles * 2048 B
#define OB_B2   1699840u      // leaf-proj B frags: 200 tiles
#define OB_B3   2109440u      // leaf-gate B frags: 150 tiles
#define OB_UT   2416640u      // tree U frags: 500 tiles * 2048 B
#define OB_BC   3440640u      // bcat: 304 floats
#define OB_ULT  3442176u      // 150*752 floats (fp32, for k_tail)
#define OB_URT  3893376u
#define OB_H0   4344576u
#define SZB_HC0 39321600u     // 128*512*150*4
#define OB_C0   (OB_H0 + SZB_HC0)
#define OB_H1   (OB_C0 + SZB_HC0)
#define SZB_HC1 19660800u
#define OB_C1   (OB_H1 + SZB_HC1)

// LDS strides (ushorts)
#define EST 328
#define CST 328
#define LSU 168
#define AST 332  // tree A stride: bank-spread

typedef short s16x8 __attribute__((ext_vector_type(8)));
typedef float f32x4 __attribute__((ext_vector_type(4)));
#define MFMA __builtin_amdgcn_mfma_f32_16x16x32_bf16

typedef unsigned short ushort_t;
typedef unsigned int uint_t;

__device__ __forceinline__ float sigmoidf_(float x) {
    return 1.0f / (1.0f + __expf(-x));
}
__device__ __forceinline__ float tanh_fast(float x) {
    x = fminf(fmaxf(x, -15.0f), 15.0f);
    float e = __expf(2.0f * x);
    return (e - 1.0f) / (e + 1.0f);
}
// split fp32 -> bf16 hi + bf16 lo (RNE both)
__device__ __forceinline__ void split_bf16(float f, ushort_t& hi, ushort_t& lo) {
    uint_t u = __float_as_uint(f);
    uint_t r = (u + 0x7fffu + ((u >> 16) & 1u)) >> 16;
    hi = (ushort_t)r;
    float d = f - __uint_as_float(r << 16);
    uint_t u2 = __float_as_uint(d);
    uint_t r2 = (u2 + 0x7fffu + ((u2 >> 16) & 1u)) >> 16;
    lo = (ushort_t)r2;
}

// conv B1 tile index: nt<12 -> kts 10..49 (40), nt>=12 -> kts 0..49 (50)
__device__ __forceinline__ int b1_tile(int nt, int kt) {
    return (nt < 12) ? nt * 40 + (kt - 10) : 480 + (nt - 12) * 50 + kt;
}

__device__ __forceinline__ void pack_frag(uint_t* out, const ushort_t* hv, const ushort_t* lv) {
    out[0] = hv[0] | (hv[1] << 16); out[1] = hv[2] | (hv[3] << 16);
    out[2] = hv[4] | (hv[5] << 16); out[3] = hv[6] | (hv[7] << 16);
    out[4] = lv[0] | (lv[1] << 16); out[5] = lv[2] | (lv[3] << 16);
    out[6] = lv[4] | (lv[5] << 16); out[7] = lv[6] | (lv[7] << 16);
}

// ---------------- k_prep (unchanged) ----------------
__global__ __launch_bounds__(256) void k_prep(
    const float* __restrict__ w3, const float* __restrict__ b3,
    const float* __restrict__ w4, const float* __restrict__ b4,
    const float* __restrict__ w5, const float* __restrict__ b5,
    const float* __restrict__ Wp, const float* __restrict__ Wx,
    const float* __restrict__ UL, const float* __restrict__ UR,
    char* __restrict__ wsb)
{
    const int W1 = 830 * 64, W2 = 200 * 64, W3 = 150 * 64, WU = 500 * 64;
    int i = blockIdx.x * 256 + threadIdx.x;
    if (i < W1) {
        int T = i >> 6, lane = i & 63;
        int nt, kt;
        if (T < 480) { nt = T / 40; kt = T % 40 + 10; }
        else { int T2 = T - 480; nt = 12 + T2 / 50; kt = T2 % 50; }
        int t = kt / 10, jjb = (kt - t * 10) * 32 + ((lane >> 4) << 3);
        int f = nt * 16 + (lane & 15);
        ushort_t hv[8], lv[8];
        #pragma unroll
        for (int e = 0; e < 8; ++e) {
            int jj = jjb + e;
            float w = 0.0f;
            if (f < 300 && jj < 300) {
                if (f < 100)      { if (t >= 1 && t <= 3) w = w3[f * 900 + jj * 3 + (t - 1)]; }
                else if (f < 200) { if (t >= 1)           w = w4[(f - 100) * 1200 + jj * 4 + (t - 1)]; }
                else              {                       w = w5[(f - 200) * 1500 + jj * 5 + t]; }
            }
            split_bf16(w, hv[e], lv[e]);
        }
        pack_frag((uint_t*)(wsb + OB_B1 + ((size_t)T * 64 + lane) * 32), hv, lv);
        return;
    }
    i -= W1;
    if (i < W2) {
        int T = i >> 6, lane = i & 63;
        int nt = T / 20, kt = T % 20;
        int h = nt * 16 + (lane & 15);
        int kb = kt * 32 + ((lane >> 4) << 3);
        ushort_t hv[8], lv[8];
        #pragma unroll
        for (int e = 0; e < 8; ++e) {
            int k = kb + e;
            float w = 0.0f;
            if (h < 150) {
                if (kt < 10) { if (k < 300) w = Wp[h * 600 + k]; }
                else { int k2 = k - 320; if (k2 < 300) w = Wp[h * 600 + 300 + k2]; }
            }
            split_bf16(w, hv[e], lv[e]);
        }
        pack_frag((uint_t*)(wsb + OB_B2 + ((size_t)T * 64 + lane) * 32), hv, lv);
        return;
    }
    i -= W2;
    if (i < W3) {
        int T = i >> 6, lane = i & 63;
        int nt3 = T / 5, kt = T % 5;
        int g = nt3 / 10, h16 = nt3 % 10;
        int h = h16 * 16 + (lane & 15);
        int kb = kt * 32 + ((lane >> 4) << 3);
        int row = (g == 0 ? 0 : (g == 1 ? 450 : 600)) + h;
        ushort_t hv[8], lv[8];
        #pragma unroll
        for (int e = 0; e < 8; ++e) {
            int k = kb + e;
            float w = (h < 150 && k < 150) ? Wx[row * 150 + k] : 0.0f;
            split_bf16(w, hv[e], lv[e]);
        }
        pack_frag((uint_t*)(wsb + OB_B3 + ((size_t)T * 64 + lane) * 32), hv, lv);
        return;
    }
    i -= W3;
    if (i < WU) {
        int T = i >> 6, lane = i & 63;
        int g = T / 100, rem = T - g * 100;
        int ht = rem / 10, kt = rem - ht * 10;
        int h = ht * 16 + (lane & 15);
        int kb = kt * 32 + ((lane >> 4) << 3);
        ushort_t hv[8], lv[8];
        #pragma unroll
        for (int e = 0; e < 8; ++e) {
            int k = kb + e;
            int half = (k >= 160);
            int j = k - half * 160;
            float w = 0.0f;
            if (h < 150 && j < 150) {
                const float* U = half ? UR : UL;
                w = U[(g * 150 + h) * 150 + j];
            }
            split_bf16(w, hv[e], lv[e]);
        }
        pack_frag((uint_t*)(wsb + OB_UT + ((size_t)T * 64 + lane) * 32), hv, lv);
        return;
    }
    i -= WU;
    if (i < 304) {
        float v = (i < 100) ? b3[i] : (i < 200 ? b4[i - 100] : (i < 300 ? b5[i - 200] : 0.0f));
        ((float*)(wsb + OB_BC))[i] = v;
        return;
    }
    i -= 304;
    if (i < 150 * UST) {
        int j = i / UST, o = i - j * UST;
        ((float*)(wsb + OB_ULT))[i] = (o < 750) ? UL[o * 150 + j] : 0.0f;
        return;
    }
    i -= 150 * UST;
    if (i < 150 * UST) {
        int j = i / UST, o = i - j * UST;
        ((float*)(wsb + OB_URT))[i] = (o < 750) ? UR[o * 150 + j] : 0.0f;
        return;
    }
}

// ---------------- k_leaf: MFMA split-bf16, TP=32, pipelined B + split accumulators ----
__global__ __launch_bounds__(640) void k_leaf(
    const int* __restrict__ x, const float* __restrict__ emb,
    const ushort_t* __restrict__ b1f, const ushort_t* __restrict__ b2f,
    const ushort_t* __restrict__ b3f, const float* __restrict__ bcat,
    const float* __restrict__ bp, const float* __restrict__ bx,
    float* __restrict__ h0, float* __restrict__ c0)
{
    __shared__ ushort_t ehi[36 * EST], elo[36 * EST];
    __shared__ ushort_t chi[32 * CST], clo[32 * CST];
    __shared__ ushort_t lhi[32 * LSU], llo[32 * LSU];

    const int b   = blockIdx.x;
    const int s0  = blockIdx.y * 32;
    const int tid = threadIdx.x;
    const int wv  = tid >> 6;
    const int lane = tid & 63;
    const int lc = lane & 15, lq = lane >> 4;

    // ---- phase 0: gather e rows (36 x 300), split to bf16 hi/lo ----
    for (int idx = tid; idx < 36 * 75; idx += 640) {
        int r = idx / 75, q = idx - r * 75;
        int sp = s0 - 2 + r;
        float4 v = make_float4(0.f, 0.f, 0.f, 0.f);
        if (sp >= 0 && sp < SS) {
            int tok = x[b * SS + sp];
            v = *reinterpret_cast<const float4*>(emb + (size_t)tok * EE + q * 4);
        }
        ushort_t h4[4], l4[4];
        split_bf16(v.x, h4[0], l4[0]); split_bf16(v.y, h4[1], l4[1]);
        split_bf16(v.z, h4[2], l4[2]); split_bf16(v.w, h4[3], l4[3]);
        *(ushort4*)&ehi[r * EST + q * 4] = make_ushort4(h4[0], h4[1], h4[2], h4[3]);
        *(ushort4*)&elo[r * EST + q * 4] = make_ushort4(l4[0], l4[1], l4[2], l4[3]);
    }
    for (int idx = tid; idx < 36 * 20; idx += 640) {
        int r = idx / 20, c = 300 + idx % 20;
        ehi[r * EST + c] = 0; elo[r * EST + c] = 0;
    }
    for (int idx = tid; idx < 32 * 16; idx += 640) {
        int r = idx / 16, c = 304 + idx % 16;
        chi[r * CST + c] = 0; clo[r * CST + c] = 0;
    }
    __syncthreads();

    // ---- phase 1: conv GEMM, 2-slot B prefetch + 3-way split accumulators ----
    {
        const int nt0 = wv;
        const int nt1 = (wv == 9) ? 18 : wv + 10;
        const bool st1 = (wv < 9);
        const int f0 = nt0 * 16 + lc;
        const int f1 = nt1 * 16 + lc;
        const float bv0 = bcat[f0];
        const float bv1 = st1 ? bcat[f1] : 0.0f;
        const f32x4 z4 = {0.f, 0.f, 0.f, 0.f};
        f32x4 s00a = {bv0, bv0, bv0, bv0}, s00b = z4, s00c = z4;
        f32x4 s01a = s00a,                 s01b = z4, s01c = z4;
        f32x4 s10a = {bv1, bv1, bv1, bv1}, s10b = z4, s10c = z4;
        f32x4 s11a = s10a,                 s11b = z4, s11c = z4;

        if (nt1 >= 12) {
            #pragma unroll
            for (int kt = 0; kt < 10; ++kt) {
                const ushort_t* p8 = b1f + ((size_t)b1_tile(nt1, kt) * 64 + lane) * 16;
                s16x8 Bh = *(const s16x8*)p8;
                s16x8 Bl = *(const s16x8*)(p8 + 8);
                int jj = kt * 32 + (lq << 3);
                s16x8 A0h = *(const s16x8*)&ehi[lc * EST + jj];
                s16x8 A0l = *(const s16x8*)&elo[lc * EST + jj];
                s16x8 A1h = *(const s16x8*)&ehi[(lc + 16) * EST + jj];
                s16x8 A1l = *(const s16x8*)&elo[(lc + 16) * EST + jj];
                s10a = MFMA(A0h, Bh, s10a, 0, 0, 0);
                s10b = MFMA(A0h, Bl, s10b, 0, 0, 0);
                s10c = MFMA(A0l, Bh, s10c, 0, 0, 0);
                s11a = MFMA(A1h, Bh, s11a, 0, 0, 0);
                s11b = MFMA(A1h, Bl, s11b, 0, 0, 0);
                s11c = MFMA(A1l, Bh, s11c, 0, 0, 0);
            }
        }

        const ushort_t* p;
        p = b1f + ((size_t)b1_tile(nt0, 10) * 64 + lane) * 16;
        s16x8 Bha0 = *(const s16x8*)p, Bla0 = *(const s16x8*)(p + 8);
        p = b1f + ((size_t)b1_tile(nt1, 10) * 64 + lane) * 16;
        s16x8 Bha1 = *(const s16x8*)p, Bla1 = *(const s16x8*)(p + 8);
        p = b1f + ((size_t)b1_tile(nt0, 11) * 64 + lane) * 16;
        s16x8 Bhb0 = *(const s16x8*)p, Blb0 = *(const s16x8*)(p + 8);
        p = b1f + ((size_t)b1_tile(nt1, 11) * 64 + lane) * 16;
        s16x8 Bhb1 = *(const s16x8*)p, Blb1 = *(const s16x8*)(p + 8);

        for (int kt = 10; kt < 50; kt += 2) {
            int k2 = (kt + 2 < 50) ? kt + 2 : 10;
            p = b1f + ((size_t)b1_tile(nt0, k2) * 64 + lane) * 16;
            s16x8 nha0 = *(const s16x8*)p, nla0 = *(const s16x8*)(p + 8);
            p = b1f + ((size_t)b1_tile(nt1, k2) * 64 + lane) * 16;
            s16x8 nha1 = *(const s16x8*)p, nla1 = *(const s16x8*)(p + 8);
            {
                int t = kt / 10;
                int jj = (kt - t * 10) * 32 + (lq << 3);
                int ra = lc + t;
                s16x8 A0h = *(const s16x8*)&ehi[ra * EST + jj];
                s16x8 A0l = *(const s16x8*)&elo[ra * EST + jj];
                s16x8 A1h = *(const s16x8*)&ehi[(ra + 16) * EST + jj];
                s16x8 A1l = *(const s16x8*)&elo[(ra + 16) * EST + jj];
                s00a = MFMA(A0h, Bha0, s00a, 0, 0, 0);
                s00b = MFMA(A0h, Bla0, s00b, 0, 0, 0);
                s00c = MFMA(A0l, Bha0, s00c, 0, 0, 0);
                s01a = MFMA(A1h, Bha0, s01a, 0, 0, 0);
                s01b = MFMA(A1h, Bla0, s01b, 0, 0, 0);
                s01c = MFMA(A1l, Bha0, s01c, 0, 0, 0);
                s10a = MFMA(A0h, Bha1, s10a, 0, 0, 0);
                s10b = MFMA(A0h, Bla1, s10b, 0, 0, 0);
                s10c = MFMA(A0l, Bha1, s10c, 0, 0, 0);
                s11a = MFMA(A1h, Bha1, s11a, 0, 0, 0);
                s11b = MFMA(A1h, Bla1, s11b, 0, 0, 0);
                s11c = MFMA(A1l, Bha1, s11c, 0, 0, 0);
            }
            int k3 = (kt + 3 < 50) ? kt + 3 : 10;
            p = b1f + ((size_t)b1_tile(nt0, k3) * 64 + lane) * 16;
            s16x8 nhb0 = *(const s16x8*)p, nlb0 = *(const s16x8*)(p + 8);
            p = b1f + ((size_t)b1_tile(nt1, k3) * 64 + lane) * 16;
            s16x8 nhb1 = *(const s16x8*)p, nlb1 = *(const s16x8*)(p + 8);
            {
                int kb2 = kt + 1;
                int t = kb2 / 10;
                int jj = (kb2 - t * 10) * 32 + (lq << 3);
                int ra = lc + t;
                s16x8 A0h = *(const s16x8*)&ehi[ra * EST + jj];
                s16x8 A0l = *(const s16x8*)&elo[ra * EST + jj];
                s16x8 A1h = *(const s16x8*)&ehi[(ra + 16) * EST + jj];
                s16x8 A1l = *(const s16x8*)&elo[(ra + 16) * EST + jj];
                s00a = MFMA(A0h, Bhb0, s00a, 0, 0, 0);
                s00b = MFMA(A0h, Blb0, s00b, 0, 0, 0);
                s00c = MFMA(A0l, Bhb0, s00c, 0, 0, 0);
                s01a = MFMA(A1h, Bhb0, s01a, 0, 0, 0);
                s01b = MFMA(A1h, Blb0, s01b, 0, 0, 0);
                s01c = MFMA(A1l, Bhb0, s01c, 0, 0, 0);
                s10a = MFMA(A0h, Bhb1, s10a, 0, 0, 0);
                s10b = MFMA(A0h, Blb1, s10b, 0, 0, 0);
                s10c = MFMA(A0l, Bhb1, s10c, 0, 0, 0);
                s11a = MFMA(A1h, Bhb1, s11a, 0, 0, 0);
                s11b = MFMA(A1h, Blb1, s11b, 0, 0, 0);
                s11c = MFMA(A1l, Bhb1, s11c, 0, 0, 0);
            }
            Bha0 = nha0; Bla0 = nla0; Bha1 = nha1; Bla1 = nla1;
            Bhb0 = nhb0; Blb0 = nlb0; Bhb1 = nhb1; Blb1 = nlb1;
        }

        f32x4 c00 = s00a + s00b + s00c;
        f32x4 c01 = s01a + s01b + s01c;
        f32x4 c10 = s10a + s10b + s10c;
        f32x4 c11 = s11a + s11b + s11c;

        #pragma unroll
        for (int r = 0; r < 4; ++r) {
            int pp = lq * 4 + r;
            ushort_t hu, lu;
            split_bf16(fmaxf(c00[r], 0.0f), hu, lu);
            chi[pp * CST + f0] = hu; clo[pp * CST + f0] = lu;
            split_bf16(fmaxf(c01[r], 0.0f), hu, lu);
            chi[(pp + 16) * CST + f0] = hu; clo[(pp + 16) * CST + f0] = lu;
            if (st1) {
                split_bf16(fmaxf(c10[r], 0.0f), hu, lu);
                chi[pp * CST + f1] = hu; clo[pp * CST + f1] = lu;
                split_bf16(fmaxf(c11[r], 0.0f), hu, lu);
                chi[(pp + 16) * CST + f1] = hu; clo[(pp + 16) * CST + f1] = lu;
            }
        }
    }
    __syncthreads();

    // ---- phase 2: leaf projection GEMM (3-way split accumulators) ----
    {
        const int hcol = wv * 16 + lc;
        const float bv = (hcol < 150) ? bp[hcol] : 0.0f;
        const f32x4 z4 = {0.f, 0.f, 0.f, 0.f};
        f32x4 d0a = {bv, bv, bv, bv}, d0b = z4, d0c = z4;
        f32x4 d1a = d0a,              d1b = z4, d1c = z4;
        #pragma unroll
        for (int kt = 0; kt < 20; ++kt) {
            s16x8 A0h, A0l, A1h, A1l;
            if (kt < 10) {
                int col = kt * 32 + (lq << 3);
                int ra = lc + 2;
                A0h = *(const s16x8*)&ehi[ra * EST + col];
                A0l = *(const s16x8*)&elo[ra * EST + col];
                A1h = *(const s16x8*)&ehi[(ra + 16) * EST + col];
                A1l = *(const s16x8*)&elo[(ra + 16) * EST + col];
            } else {
                int col = (kt - 10) * 32 + (lq << 3);
                A0h = *(const s16x8*)&chi[lc * CST + col];
                A0l = *(const s16x8*)&clo[lc * CST + col];
                A1h = *(const s16x8*)&chi[(lc + 16) * CST + col];
                A1l = *(const s16x8*)&clo[(lc + 16) * CST + col];
            }
            const ushort_t* p8 = b2f + ((size_t)(wv * 20 + kt) * 64 + lane) * 16;
            s16x8 Bh = *(const s16x8*)p8;
            s16x8 Bl = *(const s16x8*)(p8 + 8);
            d0a = MFMA(A0h, Bh, d0a, 0, 0, 0);
            d0b = MFMA(A0h, Bl, d0b, 0, 0, 0);
            d0c = MFMA(A0l, Bh, d0c, 0, 0, 0);
            d1a = MFMA(A1h, Bh, d1a, 0, 0, 0);
            d1b = MFMA(A1h, Bl, d1b, 0, 0, 0);
            d1c = MFMA(A1l, Bh, d1c, 0, 0, 0);
        }
        f32x4 d0 = d0a + d0b + d0c;
        f32x4 d1 = d1a + d1b + d1c;
        #pragma unroll
        for (int r = 0; r < 4; ++r) {
            int pp = lq * 4 + r;
            ushort_t hu, lu;
            split_bf16(d0[r], hu, lu);
            lhi[pp * LSU + hcol] = hu; llo[pp * LSU + hcol] = lu;
            split_bf16(d1[r], hu, lu);
            lhi[(pp + 16) * LSU + hcol] = hu; llo[(pp + 16) * LSU + hcol] = lu;
        }
    }
    __syncthreads();

    // ---- phase 3: leaf gates (i,o,u) GEMM + cell (2-way split accumulators) ----
    {
        const int hc = wv * 16 + lc;
        const bool hval = (hc < 150);
        const float bi = hval ? bx[hc] : 0.0f;
        const float bo = hval ? bx[450 + hc] : 0.0f;
        const float bu = hval ? bx[600 + hc] : 0.0f;
        const f32x4 z4 = {0.f, 0.f, 0.f, 0.f};
        f32x4 gi0a = {bi, bi, bi, bi}, gi0b = z4, gi1a = gi0a, gi1b = z4;
        f32x4 go0a = {bo, bo, bo, bo}, go0b = z4, go1a = go0a, go1b = z4;
        f32x4 gu0a = {bu, bu, bu, bu}, gu0b = z4, gu1a = gu0a, gu1b = z4;
        #pragma unroll
        for (int kt = 0; kt < 5; ++kt) {
            int col = kt * 32 + (lq << 3);
            s16x8 A0h = *(const s16x8*)&lhi[lc * LSU + col];
            s16x8 A0l = *(const s16x8*)&llo[lc * LSU + col];
            s16x8 A1h = *(const s16x8*)&lhi[(lc + 16) * LSU + col];
            s16x8 A1l = *(const s16x8*)&llo[(lc + 16) * LSU + col];
            const ushort_t* p8i = b3f + ((size_t)((0 + wv) * 5 + kt) * 64 + lane) * 16;
            const ushort_t* p8o = b3f + ((size_t)((10 + wv) * 5 + kt) * 64 + lane) * 16;
            const ushort_t* p8u = b3f + ((size_t)((20 + wv) * 5 + kt) * 64 + lane) * 16;
            s16x8 Bh, Bl;
            Bh = *(const s16x8*)p8i; Bl = *(const s16x8*)(p8i + 8);
            gi0a = MFMA(A0h, Bh, gi0a, 0, 0, 0); gi0b = MFMA(A0h, Bl, gi0b, 0, 0, 0); gi0a = MFMA(A0l, Bh, gi0a, 0, 0, 0);
            gi1a = MFMA(A1h, Bh, gi1a, 0, 0, 0); gi1b = MFMA(A1h, Bl, gi1b, 0, 0, 0); gi1a = MFMA(A1l, Bh, gi1a, 0, 0, 0);
            Bh = *(const s16x8*)p8o; Bl = *(const s16x8*)(p8o + 8);
            go0a = MFMA(A0h, Bh, go0a, 0, 0, 0); go0b = MFMA(A0h, Bl, go0b, 0, 0, 0); go0a = MFMA(A0l, Bh, go0a, 0, 0, 0);
            go1a = MFMA(A1h, Bh, go1a, 0, 0, 0); go1b = MFMA(A1h, Bl, go1b, 0, 0, 0); go1a = MFMA(A1l, Bh, go1a, 0, 0, 0);
            Bh = *(const s16x8*)p8u; Bl = *(const s16x8*)(p8u + 8);
            gu0a = MFMA(A0h, Bh, gu0a, 0, 0, 0); gu0b = MFMA(A0h, Bl, gu0b, 0, 0, 0); gu0a = MFMA(A0l, Bh, gu0a, 0, 0, 0);
            gu1a = MFMA(A1h, Bh, gu1a, 0, 0, 0); gu1b = MFMA(A1h, Bl, gu1b, 0, 0, 0); gu1a = MFMA(A1l, Bh, gu1a, 0, 0, 0);
        }
        if (hval) {
            f32x4 gi0 = gi0a + gi0b, gi1 = gi1a + gi1b;
            f32x4 go0 = go0a + go0b, go1 = go1a + go1b;
            f32x4 gu0 = gu0a + gu0b, gu1 = gu1a + gu1b;
            #pragma unroll
            for (int r = 0; r < 4; ++r) {
                {
                    int s = s0 + lq * 4 + r;
                    float iv = sigmoidf_(gi0[r]), ov = sigmoidf_(go0[r]), uv = tanh_fast(gu0[r]);
                    float cc = iv * uv;
                    float hh = ov * tanh_fast(cc);
                    size_t o = ((size_t)b * SS + s) * HH + hc;
                    h0[o] = hh;
                    c0[o] = cc;
                }
                {
                    int s = s0 + 16 + lq * 4 + r;
                    float iv = sigmoidf_(gi1[r]), ov = sigmoidf_(go1[r]), uv = tanh_fast(gu1[r]);
                    float cc = iv * uv;
                    float hh = ov * tanh_fast(cc);
                    size_t o = ((size_t)b * SS + s) * HH + hc;
                    h0[o] = hh;
                    c0[o] = cc;
                }
            }
        }
    }
}

// ---------------- k_tree2: MFMA split-bf16 tree level (R5/R7 proven version) -------
__global__ __launch_bounds__(640) void k_tree2(
    const float* __restrict__ in_h, const float* __restrict__ in_c,
    float* __restrict__ out_h, float* __restrict__ out_c,
    int n_out,
    const ushort_t* __restrict__ utf, const float* __restrict__ bx)
{
    __shared__ ushort_t ahi[32 * AST], alo[32 * AST];

    const int b   = blockIdx.x;
    const int m0  = blockIdx.y * 32;
    const int tid = threadIdx.x;
    const int wv  = tid >> 6, lane = tid & 63;
    const int lc  = lane & 15, lq = lane >> 4;
    const int n_in = n_out * 2;

    const float* src = in_h + ((size_t)b * n_in + 2 * m0) * HH;
    for (int idx = tid; idx < 4800; idx += 640) {
        float2 v = *(const float2*)(src + idx * 2);
        int e = idx * 2;
        int r = e / 150, k = e - r * 150;
        int base = (r >> 1) * AST + (r & 1) * 160 + k;
        ushort_t ha, la, hb, lb;
        split_bf16(v.x, ha, la);
        split_bf16(v.y, hb, lb);
        ahi[base] = ha; ahi[base + 1] = hb;
        alo[base] = la; alo[base + 1] = lb;
    }
    {
        int m = tid / 20, j = tid - (tid / 20) * 20;
        int k = (j < 10) ? (150 + j) : (310 + j - 10);
        ahi[m * AST + k] = 0; alo[m * AST + k] = 0;
    }
    __syncthreads();

    const int hc = wv * 16 + lc;
    const bool hval = (hc < 150);
    const float bi = hval ? bx[hc] : 0.f;
    const float bl = hval ? bx[150 + hc] : 0.f;
    const float br = hval ? bx[300 + hc] : 0.f;
    const float bo = hval ? bx[450 + hc] : 0.f;
    const float bu = hval ? bx[600 + hc] : 0.f;
    f32x4 ai0 = {bi, bi, bi, bi}, ai1 = ai0;
    f32x4 al0 = {bl, bl, bl, bl}, al1 = al0;
    f32x4 ar0 = {br, br, br, br}, ar1 = ar0;
    f32x4 ao0 = {bo, bo, bo, bo}, ao1 = ao0;
    f32x4 au0 = {bu, bu, bu, bu}, au1 = au0;

    const size_t gstride = (size_t)100 * 1024;
    for (int kt = 0; kt < 10; ++kt) {
        int col = kt * 32 + (lq << 3);
        s16x8 A0h = *(const s16x8*)&ahi[lc * AST + col];
        s16x8 A0l = *(const s16x8*)&alo[lc * AST + col];
        s16x8 A1h = *(const s16x8*)&ahi[(lc + 16) * AST + col];
        s16x8 A1l = *(const s16x8*)&alo[(lc + 16) * AST + col];
        const ushort_t* pb = utf + ((size_t)(wv * 10 + kt) * 64 + lane) * 16;
        s16x8 Bh, Bl;
        Bh = *(const s16x8*)pb; Bl = *(const s16x8*)(pb + 8);
        ai0 = MFMA(A0h, Bh, ai0, 0, 0, 0); ai0 = MFMA(A0h, Bl, ai0, 0, 0, 0); ai0 = MFMA(A0l, Bh, ai0, 0, 0, 0);
        ai1 = MFMA(A1h, Bh, ai1, 0, 0, 0); ai1 = MFMA(A1h, Bl, ai1, 0, 0, 0); ai1 = MFMA(A1l, Bh, ai1, 0, 0, 0);
        pb += gstride;
        Bh = *(const s16x8*)pb; Bl = *(const s16x8*)(pb + 8);
        al0 = MFMA(A0h, Bh, al0, 0, 0, 0); al0 = MFMA(A0h, Bl, al0, 0, 0, 0); al0 = MFMA(A0l, Bh, al0, 0, 0, 0);
        al1 = MFMA(A1h, Bh, al1, 0, 0, 0); al1 = MFMA(A1h, Bl, al1, 0, 0, 0); al1 = MFMA(A1l, Bh, al1, 0, 0, 0);
        pb += gstride;
        Bh = *(const s16x8*)pb; Bl = *(const s16x8*)(pb + 8);
        ar0 = MFMA(A0h, Bh, ar0, 0, 0, 0); ar0 = MFMA(A0h, Bl, ar0, 0, 0, 0); ar0 = MFMA(A0l, Bh, ar0, 0, 0, 0);
        ar1 = MFMA(A1h, Bh, ar1, 0, 0, 0); ar1 = MFMA(A1h, Bl, ar1, 0, 0, 0); ar1 = MFMA(A1l, Bh, ar1, 0, 0, 0);
        pb += gstride;
        Bh = *(const s16x8*)pb; Bl = *(const s16x8*)(pb + 8);
        ao0 = MFMA(A0h, Bh, ao0, 0, 0, 0); ao0 = MFMA(A0h, Bl, ao0, 0, 0, 0); ao0 = MFMA(A0l, Bh, ao0, 0, 0, 0);
        ao1 = MFMA(A1h, Bh, ao1, 0, 0, 0); ao1 = MFMA(A1h, Bl, ao1, 0, 0, 0); ao1 = MFMA(A1l, Bh, ao1, 0, 0, 0);
        pb += gstride;
        Bh = *(const s16x8*)pb; Bl = *(const s16x8*)(pb + 8);
        au0 = MFMA(A0h, Bh, au0, 0, 0, 0); au0 = MFMA(A0h, Bl, au0, 0, 0, 0); au0 = MFMA(A0l, Bh, au0, 0, 0, 0);
        au1 = MFMA(A1h, Bh, au1, 0, 0, 0); au1 = MFMA(A1h, Bl, au1, 0, 0, 0); au1 = MFMA(A1l, Bh, au1, 0, 0, 0);
    }

    if (hval) {
        #pragma unroll
        for (int r = 0; r < 4; ++r) {
            int ml = lq * 4 + r;
            {
                int m = m0 + ml;
                size_t cb = ((size_t)b * n_in + 2 * m) * HH + hc;
                float iv = sigmoidf_(ai0[r]);
                float fl = sigmoidf_(al0[r]);
                float fr = sigmoidf_(ar0[r]);
                float ov = sigmoidf_(ao0[r]);
                float uv = tanh_fast(au0[r]);
                float cc = iv * uv + fl * in_c[cb] + fr * in_c[cb + HH];
                size_t ob = ((size_t)b * n_out + m) * HH + hc;
                out_h[ob] = ov * tanh_fast(cc);
                out_c[ob] = cc;
            }
            {
                int m = m0 + 16 + ml;
                size_t cb = ((size_t)b * n_in + 2 * m) * HH + hc;
                float iv = sigmoidf_(ai1[r]);
                float fl = sigmoidf_(al1[r]);
                float fr = sigmoidf_(ar1[r]);
                float ov = sigmoidf_(ao1[r]);
                float uv = tanh_fast(au1[r]);
                float cc = iv * uv + fl * in_c[cb] + fr * in_c[cb + HH];
                size_t ob = ((size_t)b * n_out + m) * HH + hc;
                out_h[ob] = ov * tanh_fast(cc);
                out_c[ob] = cc;
            }
        }
    }
}

// ---------------- k_tail: levels 16..1 in LDS + head MLP (fp32, unchanged) ---------
__global__ __launch_bounds__(384) void k_tail(
    const float* __restrict__ in_h, const float* __restrict__ in_c,
    const float* __restrict__ ULT, const float* __restrict__ URT,
    const float* __restrict__ bx,
    const float* __restrict__ W1, const float* __restrict__ b1,
    const float* __restrict__ W2, const float* __restrict__ b2,
    float* __restrict__ out)
{
    __shared__ float pool[96 * LST + TN * GS];
    float* Ah = pool;
    float* Ac = Ah + 32 * LST;
    float* Bh = Ac + 32 * LST;
    float* Bc = Bh + 16 * LST;
    float* gs = Bc + 16 * LST;
    __shared__ float z_s[80];

    const int b   = blockIdx.x;
    const int tid = threadIdx.x;

    for (int idx = tid; idx < 32 * HH; idx += 384) {
        int p = idx / HH, j = idx - p * HH;
        size_t base = ((size_t)b * 32 + p) * HH + j;
        Ah[p * LST + j] = in_h[base];
        Ac[p * LST + j] = in_c[base];
    }

    const int o1 = tid, o2 = tid + 384;
    const int o2c = (o2 < 752) ? o2 : 751;
    const float bx1 = bx[o1];
    const float bx2 = (o2 < 750) ? bx[o2] : 0.0f;
    const float* ul1 = ULT + o1; const float* ur1 = URT + o1;
    const float* ul2 = ULT + o2c; const float* ur2 = URT + o2c;

    float* curh = Ah; float* curc = Ac;
    float* nxth = Bh; float* nxtc = Bc;

    for (int n = 16; n >= 1; n >>= 1) {
        __syncthreads();
        {
            float a1[TN], a2[TN];
            #pragma unroll
            for (int m = 0; m < TN; ++m) { a1[m] = bx1; a2[m] = bx2; }
            for (int j = 0; j < 150; j += 2) {
                int r0 = j * UST, r1 = (j + 1) * UST;
                float wl1a = ul1[r0], wl1b = ul1[r1];
                float wr1a = ur1[r0], wr1b = ur1[r1];
                float wl2a = ul2[r0], wl2b = ul2[r1];
                float wr2a = ur2[r0], wr2b = ur2[r1];
                #pragma unroll
                for (int m = 0; m < TN; ++m) {
                    float2 lv = *(const float2*)(curh + (2 * m) * LST + j);
                    float2 rv = *(const float2*)(curh + (2 * m + 1) * LST + j);
                    a1[m] += lv.x * wl1a + lv.y * wl1b + rv.x * wr1a + rv.y * wr1b;
                    a2[m] += lv.x * wl2a + lv.y * wl2b + rv.x * wr2a + rv.y * wr2b;
                }
            }
            #pragma unroll
            for (int m = 0; m < TN; ++m) {
                if (m < n) {
                    gs[m * GS + o1] = a1[m];
                    if (o2 < 750) gs[m * GS + o2] = a2[m];
                }
            }
        }
        __syncthreads();
        for (int idx = tid; idx < n * HH; idx += 384) {
            int m = idx / HH, h = idx - m * HH;
            float iv = sigmoidf_(gs[m * GS + h]);
            float fL = sigmoidf_(gs[m * GS + 150 + h]);
            float fR = sigmoidf_(gs[m * GS + 300 + h]);
            float ov = sigmoidf_(gs[m * GS + 450 + h]);
            float uv = tanh_fast(gs[m * GS + 600 + h]);
            float cc = iv * uv + fL * curc[2 * m * LST + h] + fR * curc[(2 * m + 1) * LST + h];
            nxth[m * LST + h] = ov * tanh_fast(cc);
            nxtc[m * LST + h] = cc;
        }
        float* t;
        t = curh; curh = nxth; nxth = t;
        t = curc; curc = nxtc; nxtc = t;
    }
    __syncthreads();

    if (tid < 75) {
        const float* w = W1 + (size_t)tid * 150;
        float acc = b1[tid];
        for (int j = 0; j < 150; ++j) acc += curh[j] * w[j];
        z_s[tid] = fmaxf(acc, 0.0f);
    }
    __syncthreads();
    if (tid < 3) {
        const float* w = W2 + (size_t)tid * 75;
        float acc = b2[tid];
        for (int j = 0; j < 75; ++j) acc += z_s[j] * w[j];
        out[(size_t)b * 3 + tid] = acc;
    }
}

extern "C" void kernel_launch(void* const* d_in, const int* in_sizes, int n_in,
                              void* d_out, int out_size, void* d_ws, size_t ws_size,
                              hipStream_t stream) {
    const int*   x   = (const int*)  d_in[0];
    const float* emb = (const float*)d_in[1];
    const float* w3  = (const float*)d_in[2];
    const float* b3  = (const float*)d_in[3];
    const float* w4  = (const float*)d_in[4];
    const float* b4  = (const float*)d_in[5];
    const float* w5  = (const float*)d_in[6];
    const float* b5  = (const float*)d_in[7];
    const float* Wp  = (const float*)d_in[8];
    const float* bp  = (const float*)d_in[9];
    const float* Wx  = (const float*)d_in[10];
    const float* bx  = (const float*)d_in[11];
    const float* UL  = (const float*)d_in[12];
    const float* UR  = (const float*)d_in[13];
    const float* W1  = (const float*)d_in[14];
    const float* b1  = (const float*)d_in[15];
    const float* W2  = (const float*)d_in[16];
    const float* b2  = (const float*)d_in[17];
    float* out = (float*)d_out;

    char* wsb = (char*)d_ws;
    const ushort_t* b1f = (const ushort_t*)(wsb + OB_B1);
    const ushort_t* b2f = (const ushort_t*)(wsb + OB_B2);
    const ushort_t* b3f = (const ushort_t*)(wsb + OB_B3);
    const ushort_t* utf = (const ushort_t*)(wsb + OB_UT);
    const float* bcat = (const float*)(wsb + OB_BC);
    const float* ULT  = (const float*)(wsb + OB_ULT);
    const float* URT  = (const float*)(wsb + OB_URT);
    float* h0 = (float*)(wsb + OB_H0);
    float* c0 = (float*)(wsb + OB_C0);
    float* h1 = (float*)(wsb + OB_H1);
    float* c1 = (float*)(wsb + OB_C1);

    {
        int total = 830 * 64 + 200 * 64 + 150 * 64 + 500 * 64 + 304 + 2 * 150 * UST;
        k_prep<<<(total + 255) / 256, 256, 0, stream>>>(
            w3, b3, w4, b4, w5, b5, Wp, Wx, UL, UR, wsb);
    }

    k_leaf<<<dim3(BB, SS / 32), 640, 0, stream>>>(
        x, emb, b1f, b2f, b3f, bcat, bp, bx, h0, c0);

    k_tree2<<<dim3(BB, 8), 640, 0, stream>>>(h0, c0, h1, c1, 256, utf, bx);
    k_tree2<<<dim3(BB, 4), 640, 0, stream>>>(h1, c1, h0, c0, 128, utf, bx);
    k_tree2<<<dim3(BB, 2), 640, 0, stream>>>(h0, c0, h1, c1,  64, utf, bx);
    k_tree2<<<dim3(BB, 1), 640, 0, stream>>>(h1, c1, h0, c0,  32, utf, bx);

    k_tail<<<BB, 384, 0, stream>>>(h0, c0, ULT, URT, bx, W1, b1, W2, b2, out);
}

// Round 10
// 601.850 us; speedup vs baseline: 1.2902x; 1.2383x over previous
//
#include <hip/hip_runtime.h>
#include <math.h>

#define BB 128
#define SS 512
#define EE 300
#define HH 150
#define TN 16
#define LST 152  // tail LDS row stride (floats)
#define GS 752   // tail gate buffer row stride
#define UST 752  // transposed UL/UR row stride (cols 750..751 zero)

// ---- workspace byte offsets ----
#define OB_B1   0u
#define OB_B2   1699840u
#define OB_B3   2109440u
#define OB_UT   2416640u
#define OB_BC   3440640u
#define OB_ULT  3442176u
#define OB_URT  3893376u
#define OB_H0   4344576u
#define SZB_HC0 39321600u
#define OB_C0   (OB_H0 + SZB_HC0)
#define OB_H1   (OB_C0 + SZB_HC0)
#define SZB_HC1 19660800u
#define OB_C1   (OB_H1 + SZB_HC1)

// LDS strides (ushorts)
#define EST 328
#define CST 328
#define LSU 168
#define AST 332

typedef short s16x8 __attribute__((ext_vector_type(8)));
typedef float f32x4 __attribute__((ext_vector_type(4)));
#define MFMA __builtin_amdgcn_mfma_f32_16x16x32_bf16

typedef unsigned short ushort_t;
typedef unsigned int uint_t;

__device__ __forceinline__ float sigmoidf_(float x) {
    return 1.0f / (1.0f + __expf(-x));
}
__device__ __forceinline__ float tanh_fast(float x) {
    x = fminf(fmaxf(x, -15.0f), 15.0f);
    float e = __expf(2.0f * x);
    return (e - 1.0f) / (e + 1.0f);
}
__device__ __forceinline__ void split_bf16(float f, ushort_t& hi, ushort_t& lo) {
    uint_t u = __float_as_uint(f);
    uint_t r = (u + 0x7fffu + ((u >> 16) & 1u)) >> 16;
    hi = (ushort_t)r;
    float d = f - __uint_as_float(r << 16);
    uint_t u2 = __float_as_uint(d);
    uint_t r2 = (u2 + 0x7fffu + ((u2 >> 16) & 1u)) >> 16;
    lo = (ushort_t)r2;
}

__device__ __forceinline__ int b1_tile(int nt, int kt) {
    return (nt < 12) ? nt * 40 + (kt - 10) : 480 + (nt - 12) * 50 + kt;
}

__device__ __forceinline__ void pack_frag(uint_t* out, const ushort_t* hv, const ushort_t* lv) {
    out[0] = hv[0] | (hv[1] << 16); out[1] = hv[2] | (hv[3] << 16);
    out[2] = hv[4] | (hv[5] << 16); out[3] = hv[6] | (hv[7] << 16);
    out[4] = lv[0] | (lv[1] << 16); out[5] = lv[2] | (lv[3] << 16);
    out[6] = lv[4] | (lv[5] << 16); out[7] = lv[6] | (lv[7] << 16);
}

// ---------------- k_prep (unchanged) ----------------
__global__ __launch_bounds__(256) void k_prep(
    const float* __restrict__ w3, const float* __restrict__ b3,
    const float* __restrict__ w4, const float* __restrict__ b4,
    const float* __restrict__ w5, const float* __restrict__ b5,
    const float* __restrict__ Wp, const float* __restrict__ Wx,
    const float* __restrict__ UL, const float* __restrict__ UR,
    char* __restrict__ wsb)
{
    const int W1 = 830 * 64, W2 = 200 * 64, W3 = 150 * 64, WU = 500 * 64;
    int i = blockIdx.x * 256 + threadIdx.x;
    if (i < W1) {
        int T = i >> 6, lane = i & 63;
        int nt, kt;
        if (T < 480) { nt = T / 40; kt = T % 40 + 10; }
        else { int T2 = T - 480; nt = 12 + T2 / 50; kt = T2 % 50; }
        int t = kt / 10, jjb = (kt - t * 10) * 32 + ((lane >> 4) << 3);
        int f = nt * 16 + (lane & 15);
        ushort_t hv[8], lv[8];
        #pragma unroll
        for (int e = 0; e < 8; ++e) {
            int jj = jjb + e;
            float w = 0.0f;
            if (f < 300 && jj < 300) {
                if (f < 100)      { if (t >= 1 && t <= 3) w = w3[f * 900 + jj * 3 + (t - 1)]; }
                else if (f < 200) { if (t >= 1)           w = w4[(f - 100) * 1200 + jj * 4 + (t - 1)]; }
                else              {                       w = w5[(f - 200) * 1500 + jj * 5 + t]; }
            }
            split_bf16(w, hv[e], lv[e]);
        }
        pack_frag((uint_t*)(wsb + OB_B1 + ((size_t)T * 64 + lane) * 32), hv, lv);
        return;
    }
    i -= W1;
    if (i < W2) {
        int T = i >> 6, lane = i & 63;
        int nt = T / 20, kt = T % 20;
        int h = nt * 16 + (lane & 15);
        int kb = kt * 32 + ((lane >> 4) << 3);
        ushort_t hv[8], lv[8];
        #pragma unroll
        for (int e = 0; e < 8; ++e) {
            int k = kb + e;
            float w = 0.0f;
            if (h < 150) {
                if (kt < 10) { if (k < 300) w = Wp[h * 600 + k]; }
                else { int k2 = k - 320; if (k2 < 300) w = Wp[h * 600 + 300 + k2]; }
            }
            split_bf16(w, hv[e], lv[e]);
        }
        pack_frag((uint_t*)(wsb + OB_B2 + ((size_t)T * 64 + lane) * 32), hv, lv);
        return;
    }
    i -= W2;
    if (i < W3) {
        int T = i >> 6, lane = i & 63;
        int nt3 = T / 5, kt = T % 5;
        int g = nt3 / 10, h16 = nt3 % 10;
        int h = h16 * 16 + (lane & 15);
        int kb = kt * 32 + ((lane >> 4) << 3);
        int row = (g == 0 ? 0 : (g == 1 ? 450 : 600)) + h;
        ushort_t hv[8], lv[8];
        #pragma unroll
        for (int e = 0; e < 8; ++e) {
            int k = kb + e;
            float w = (h < 150 && k < 150) ? Wx[row * 150 + k] : 0.0f;
            split_bf16(w, hv[e], lv[e]);
        }
        pack_frag((uint_t*)(wsb + OB_B3 + ((size_t)T * 64 + lane) * 32), hv, lv);
        return;
    }
    i -= W3;
    if (i < WU) {
        int T = i >> 6, lane = i & 63;
        int g = T / 100, rem = T - g * 100;
        int ht = rem / 10, kt = rem - ht * 10;
        int h = ht * 16 + (lane & 15);
        int kb = kt * 32 + ((lane >> 4) << 3);
        ushort_t hv[8], lv[8];
        #pragma unroll
        for (int e = 0; e < 8; ++e) {
            int k = kb + e;
            int half = (k >= 160);
            int j = k - half * 160;
            float w = 0.0f;
            if (h < 150 && j < 150) {
                const float* U = half ? UR : UL;
                w = U[(g * 150 + h) * 150 + j];
            }
            split_bf16(w, hv[e], lv[e]);
        }
        pack_frag((uint_t*)(wsb + OB_UT + ((size_t)T * 64 + lane) * 32), hv, lv);
        return;
    }
    i -= WU;
    if (i < 304) {
        float v = (i < 100) ? b3[i] : (i < 200 ? b4[i - 100] : (i < 300 ? b5[i - 200] : 0.0f));
        ((float*)(wsb + OB_BC))[i] = v;
        return;
    }
    i -= 304;
    if (i < 150 * UST) {
        int j = i / UST, o = i - j * UST;
        ((float*)(wsb + OB_ULT))[i] = (o < 750) ? UL[o * 150 + j] : 0.0f;
        return;
    }
    i -= 150 * UST;
    if (i < 150 * UST) {
        int j = i / UST, o = i - j * UST;
        ((float*)(wsb + OB_URT))[i] = (o < 750) ? UR[o * 150 + j] : 0.0f;
        return;
    }
}

// A-fragment loader (phase 1): rows lc+t / lc+16+t, cols for kt
#define LDA(kt_, d0h, d0l, d1h, d1l) { \
    int t_ = (kt_) / 10; \
    int jj_ = ((kt_) - t_ * 10) * 32 + (lq << 3); \
    int ra_ = lc + t_; \
    d0h = *(const s16x8*)&ehi[ra_ * EST + jj_]; \
    d0l = *(const s16x8*)&elo[ra_ * EST + jj_]; \
    d1h = *(const s16x8*)&ehi[(ra_ + 16) * EST + jj_]; \
    d1l = *(const s16x8*)&elo[(ra_ + 16) * EST + jj_]; }

// ---------------- k_leaf: MFMA split-bf16, TP=32, A+B register pipelining ----
__global__ __launch_bounds__(640) void k_leaf(
    const int* __restrict__ x, const float* __restrict__ emb,
    const ushort_t* __restrict__ b1f, const ushort_t* __restrict__ b2f,
    const ushort_t* __restrict__ b3f, const float* __restrict__ bcat,
    const float* __restrict__ bp, const float* __restrict__ bx,
    float* __restrict__ h0, float* __restrict__ c0)
{
    __shared__ ushort_t ehi[36 * EST], elo[36 * EST];
    __shared__ ushort_t chi[32 * CST], clo[32 * CST];
    __shared__ ushort_t lhi[32 * LSU], llo[32 * LSU];

    const int b   = blockIdx.x;
    const int s0  = blockIdx.y * 32;
    const int tid = threadIdx.x;
    const int wv  = tid >> 6;
    const int lane = tid & 63;
    const int lc = lane & 15, lq = lane >> 4;

    // ---- phase 0: gather e rows (36 x 300), split to bf16 hi/lo ----
    for (int idx = tid; idx < 36 * 75; idx += 640) {
        int r = idx / 75, q = idx - r * 75;
        int sp = s0 - 2 + r;
        float4 v = make_float4(0.f, 0.f, 0.f, 0.f);
        if (sp >= 0 && sp < SS) {
            int tok = x[b * SS + sp];
            v = *reinterpret_cast<const float4*>(emb + (size_t)tok * EE + q * 4);
        }
        ushort_t h4[4], l4[4];
        split_bf16(v.x, h4[0], l4[0]); split_bf16(v.y, h4[1], l4[1]);
        split_bf16(v.z, h4[2], l4[2]); split_bf16(v.w, h4[3], l4[3]);
        *(ushort4*)&ehi[r * EST + q * 4] = make_ushort4(h4[0], h4[1], h4[2], h4[3]);
        *(ushort4*)&elo[r * EST + q * 4] = make_ushort4(l4[0], l4[1], l4[2], l4[3]);
    }
    for (int idx = tid; idx < 36 * 20; idx += 640) {
        int r = idx / 20, c = 300 + idx % 20;
        ehi[r * EST + c] = 0; elo[r * EST + c] = 0;
    }
    for (int idx = tid; idx < 32 * 16; idx += 640) {
        int r = idx / 16, c = 304 + idx % 16;
        chi[r * CST + c] = 0; clo[r * CST + c] = 0;
    }
    __syncthreads();

    // ---- phase 1: conv GEMM, 2-slot A+B register pipeline, split accumulators ----
    {
        const int nt0 = wv;
        const int nt1 = (wv == 9) ? 18 : wv + 10;
        const bool st1 = (wv < 9);
        const int f0 = nt0 * 16 + lc;
        const int f1 = nt1 * 16 + lc;
        const float bv0 = bcat[f0];
        const float bv1 = st1 ? bcat[f1] : 0.0f;
        const f32x4 z4 = {0.f, 0.f, 0.f, 0.f};
        f32x4 s00a = {bv0, bv0, bv0, bv0}, s00b = z4, s00c = z4;
        f32x4 s01a = s00a,                 s01b = z4, s01c = z4;
        f32x4 s10a = {bv1, bv1, bv1, bv1}, s10b = z4, s10c = z4;
        f32x4 s11a = s10a,                 s11b = z4, s11c = z4;

        if (nt1 >= 12) {
            #pragma unroll
            for (int kt = 0; kt < 10; ++kt) {
                const ushort_t* p8 = b1f + ((size_t)b1_tile(nt1, kt) * 64 + lane) * 16;
                s16x8 Bh = *(const s16x8*)p8;
                s16x8 Bl = *(const s16x8*)(p8 + 8);
                int jj = kt * 32 + (lq << 3);
                s16x8 A0h = *(const s16x8*)&ehi[lc * EST + jj];
                s16x8 A0l = *(const s16x8*)&elo[lc * EST + jj];
                s16x8 A1h = *(const s16x8*)&ehi[(lc + 16) * EST + jj];
                s16x8 A1l = *(const s16x8*)&elo[(lc + 16) * EST + jj];
                s10a = MFMA(A0h, Bh, s10a, 0, 0, 0);
                s10b = MFMA(A0h, Bl, s10b, 0, 0, 0);
                s10c = MFMA(A0l, Bh, s10c, 0, 0, 0);
                s11a = MFMA(A1h, Bh, s11a, 0, 0, 0);
                s11b = MFMA(A1h, Bl, s11b, 0, 0, 0);
                s11c = MFMA(A1l, Bh, s11c, 0, 0, 0);
            }
        }

        // prime B (2 deep) and A (2 deep)
        const ushort_t* p;
        p = b1f + ((size_t)b1_tile(nt0, 10) * 64 + lane) * 16;
        s16x8 Bha0 = *(const s16x8*)p, Bla0 = *(const s16x8*)(p + 8);
        p = b1f + ((size_t)b1_tile(nt1, 10) * 64 + lane) * 16;
        s16x8 Bha1 = *(const s16x8*)p, Bla1 = *(const s16x8*)(p + 8);
        p = b1f + ((size_t)b1_tile(nt0, 11) * 64 + lane) * 16;
        s16x8 Bhb0 = *(const s16x8*)p, Blb0 = *(const s16x8*)(p + 8);
        p = b1f + ((size_t)b1_tile(nt1, 11) * 64 + lane) * 16;
        s16x8 Bhb1 = *(const s16x8*)p, Blb1 = *(const s16x8*)(p + 8);

        s16x8 Pa0h, Pa0l, Pa1h, Pa1l, Pb0h, Pb0l, Pb1h, Pb1l;
        LDA(10, Pa0h, Pa0l, Pa1h, Pa1l);
        LDA(11, Pb0h, Pb0l, Pb1h, Pb1l);

        for (int kt = 10; kt < 50; kt += 2) {
            int k2 = (kt + 2 < 50) ? kt + 2 : 10;
            p = b1f + ((size_t)b1_tile(nt0, k2) * 64 + lane) * 16;
            s16x8 nha0 = *(const s16x8*)p, nla0 = *(const s16x8*)(p + 8);
            p = b1f + ((size_t)b1_tile(nt1, k2) * 64 + lane) * 16;
            s16x8 nha1 = *(const s16x8*)p, nla1 = *(const s16x8*)(p + 8);

            // compute kt with pre-loaded A (Pa*)
            s00a = MFMA(Pa0h, Bha0, s00a, 0, 0, 0);
            s00b = MFMA(Pa0h, Bla0, s00b, 0, 0, 0);
            s00c = MFMA(Pa0l, Bha0, s00c, 0, 0, 0);
            s01a = MFMA(Pa1h, Bha0, s01a, 0, 0, 0);
            s01b = MFMA(Pa1h, Bla0, s01b, 0, 0, 0);
            s01c = MFMA(Pa1l, Bha0, s01c, 0, 0, 0);
            s10a = MFMA(Pa0h, Bha1, s10a, 0, 0, 0);
            s10b = MFMA(Pa0h, Bla1, s10b, 0, 0, 0);
            s10c = MFMA(Pa0l, Bha1, s10c, 0, 0, 0);
            s11a = MFMA(Pa1h, Bha1, s11a, 0, 0, 0);
            s11b = MFMA(Pa1h, Bla1, s11b, 0, 0, 0);
            s11c = MFMA(Pa1l, Bha1, s11c, 0, 0, 0);

            // prefetch A(kt+2) into Pa (LDS latency hidden under kt+1's MFMAs)
            LDA(k2, Pa0h, Pa0l, Pa1h, Pa1l);

            int k3 = (kt + 3 < 50) ? kt + 3 : 11;
            p = b1f + ((size_t)b1_tile(nt0, k3) * 64 + lane) * 16;
            s16x8 nhb0 = *(const s16x8*)p, nlb0 = *(const s16x8*)(p + 8);
            p = b1f + ((size_t)b1_tile(nt1, k3) * 64 + lane) * 16;
            s16x8 nhb1 = *(const s16x8*)p, nlb1 = *(const s16x8*)(p + 8);

            // compute kt+1 with pre-loaded A (Pb*)
            s00a = MFMA(Pb0h, Bhb0, s00a, 0, 0, 0);
            s00b = MFMA(Pb0h, Blb0, s00b, 0, 0, 0);
            s00c = MFMA(Pb0l, Bhb0, s00c, 0, 0, 0);
            s01a = MFMA(Pb1h, Bhb0, s01a, 0, 0, 0);
            s01b = MFMA(Pb1h, Blb0, s01b, 0, 0, 0);
            s01c = MFMA(Pb1l, Bhb0, s01c, 0, 0, 0);
            s10a = MFMA(Pb0h, Bhb1, s10a, 0, 0, 0);
            s10b = MFMA(Pb0h, Blb1, s10b, 0, 0, 0);
            s10c = MFMA(Pb0l, Bhb1, s10c, 0, 0, 0);
            s11a = MFMA(Pb1h, Bhb1, s11a, 0, 0, 0);
            s11b = MFMA(Pb1h, Blb1, s11b, 0, 0, 0);
            s11c = MFMA(Pb1l, Bhb1, s11c, 0, 0, 0);

            // prefetch A(kt+3) into Pb
            LDA(k3, Pb0h, Pb0l, Pb1h, Pb1l);

            Bha0 = nha0; Bla0 = nla0; Bha1 = nha1; Bla1 = nla1;
            Bhb0 = nhb0; Blb0 = nlb0; Bhb1 = nhb1; Blb1 = nlb1;
        }

        f32x4 c00 = s00a + s00b + s00c;
        f32x4 c01 = s01a + s01b + s01c;
        f32x4 c10 = s10a + s10b + s10c;
        f32x4 c11 = s11a + s11b + s11c;

        #pragma unroll
        for (int r = 0; r < 4; ++r) {
            int pp = lq * 4 + r;
            ushort_t hu, lu;
            split_bf16(fmaxf(c00[r], 0.0f), hu, lu);
            chi[pp * CST + f0] = hu; clo[pp * CST + f0] = lu;
            split_bf16(fmaxf(c01[r], 0.0f), hu, lu);
            chi[(pp + 16) * CST + f0] = hu; clo[(pp + 16) * CST + f0] = lu;
            if (st1) {
                split_bf16(fmaxf(c10[r], 0.0f), hu, lu);
                chi[pp * CST + f1] = hu; clo[pp * CST + f1] = lu;
                split_bf16(fmaxf(c11[r], 0.0f), hu, lu);
                chi[(pp + 16) * CST + f1] = hu; clo[(pp + 16) * CST + f1] = lu;
            }
        }
    }
    __syncthreads();

    // ---- phase 2: leaf projection GEMM (3-way split accumulators) ----
    {
        const int hcol = wv * 16 + lc;
        const float bv = (hcol < 150) ? bp[hcol] : 0.0f;
        const f32x4 z4 = {0.f, 0.f, 0.f, 0.f};
        f32x4 d0a = {bv, bv, bv, bv}, d0b = z4, d0c = z4;
        f32x4 d1a = d0a,              d1b = z4, d1c = z4;
        #pragma unroll
        for (int kt = 0; kt < 20; ++kt) {
            s16x8 A0h, A0l, A1h, A1l;
            if (kt < 10) {
                int col = kt * 32 + (lq << 3);
                int ra = lc + 2;
                A0h = *(const s16x8*)&ehi[ra * EST + col];
                A0l = *(const s16x8*)&elo[ra * EST + col];
                A1h = *(const s16x8*)&ehi[(ra + 16) * EST + col];
                A1l = *(const s16x8*)&elo[(ra + 16) * EST + col];
            } else {
                int col = (kt - 10) * 32 + (lq << 3);
                A0h = *(const s16x8*)&chi[lc * CST + col];
                A0l = *(const s16x8*)&clo[lc * CST + col];
                A1h = *(const s16x8*)&chi[(lc + 16) * CST + col];
                A1l = *(const s16x8*)&clo[(lc + 16) * CST + col];
            }
            const ushort_t* p8 = b2f + ((size_t)(wv * 20 + kt) * 64 + lane) * 16;
            s16x8 Bh = *(const s16x8*)p8;
            s16x8 Bl = *(const s16x8*)(p8 + 8);
            d0a = MFMA(A0h, Bh, d0a, 0, 0, 0);
            d0b = MFMA(A0h, Bl, d0b, 0, 0, 0);
            d0c = MFMA(A0l, Bh, d0c, 0, 0, 0);
            d1a = MFMA(A1h, Bh, d1a, 0, 0, 0);
            d1b = MFMA(A1h, Bl, d1b, 0, 0, 0);
            d1c = MFMA(A1l, Bh, d1c, 0, 0, 0);
        }
        f32x4 d0 = d0a + d0b + d0c;
        f32x4 d1 = d1a + d1b + d1c;
        #pragma unroll
        for (int r = 0; r < 4; ++r) {
            int pp = lq * 4 + r;
            ushort_t hu, lu;
            split_bf16(d0[r], hu, lu);
            lhi[pp * LSU + hcol] = hu; llo[pp * LSU + hcol] = lu;
            split_bf16(d1[r], hu, lu);
            lhi[(pp + 16) * LSU + hcol] = hu; llo[(pp + 16) * LSU + hcol] = lu;
        }
    }
    __syncthreads();

    // ---- phase 3: leaf gates (i,o,u) GEMM + cell ----
    {
        const int hc = wv * 16 + lc;
        const bool hval = (hc < 150);
        const float bi = hval ? bx[hc] : 0.0f;
        const float bo = hval ? bx[450 + hc] : 0.0f;
        const float bu = hval ? bx[600 + hc] : 0.0f;
        const f32x4 z4 = {0.f, 0.f, 0.f, 0.f};
        f32x4 gi0a = {bi, bi, bi, bi}, gi0b = z4, gi1a = gi0a, gi1b = z4;
        f32x4 go0a = {bo, bo, bo, bo}, go0b = z4, go1a = go0a, go1b = z4;
        f32x4 gu0a = {bu, bu, bu, bu}, gu0b = z4, gu1a = gu0a, gu1b = z4;
        #pragma unroll
        for (int kt = 0; kt < 5; ++kt) {
            int col = kt * 32 + (lq << 3);
            s16x8 A0h = *(const s16x8*)&lhi[lc * LSU + col];
            s16x8 A0l = *(const s16x8*)&llo[lc * LSU + col];
            s16x8 A1h = *(const s16x8*)&lhi[(lc + 16) * LSU + col];
            s16x8 A1l = *(const s16x8*)&llo[(lc + 16) * LSU + col];
            const ushort_t* p8i = b3f + ((size_t)((0 + wv) * 5 + kt) * 64 + lane) * 16;
            const ushort_t* p8o = b3f + ((size_t)((10 + wv) * 5 + kt) * 64 + lane) * 16;
            const ushort_t* p8u = b3f + ((size_t)((20 + wv) * 5 + kt) * 64 + lane) * 16;
            s16x8 Bh, Bl;
            Bh = *(const s16x8*)p8i; Bl = *(const s16x8*)(p8i + 8);
            gi0a = MFMA(A0h, Bh, gi0a, 0, 0, 0); gi0b = MFMA(A0h, Bl, gi0b, 0, 0, 0); gi0a = MFMA(A0l, Bh, gi0a, 0, 0, 0);
            gi1a = MFMA(A1h, Bh, gi1a, 0, 0, 0); gi1b = MFMA(A1h, Bl, gi1b, 0, 0, 0); gi1a = MFMA(A1l, Bh, gi1a, 0, 0, 0);
            Bh = *(const s16x8*)p8o; Bl = *(const s16x8*)(p8o + 8);
            go0a = MFMA(A0h, Bh, go0a, 0, 0, 0); go0b = MFMA(A0h, Bl, go0b, 0, 0, 0); go0a = MFMA(A0l, Bh, go0a, 0, 0, 0);
            go1a = MFMA(A1h, Bh, go1a, 0, 0, 0); go1b = MFMA(A1h, Bl, go1b, 0, 0, 0); go1a = MFMA(A1l, Bh, go1a, 0, 0, 0);
            Bh = *(const s16x8*)p8u; Bl = *(const s16x8*)(p8u + 8);
            gu0a = MFMA(A0h, Bh, gu0a, 0, 0, 0); gu0b = MFMA(A0h, Bl, gu0b, 0, 0, 0); gu0a = MFMA(A0l, Bh, gu0a, 0, 0, 0);
            gu1a = MFMA(A1h, Bh, gu1a, 0, 0, 0); gu1b = MFMA(A1h, Bl, gu1b, 0, 0, 0); gu1a = MFMA(A1l, Bh, gu1a, 0, 0, 0);
        }
        if (hval) {
            f32x4 gi0 = gi0a + gi0b, gi1 = gi1a + gi1b;
            f32x4 go0 = go0a + go0b, go1 = go1a + go1b;
            f32x4 gu0 = gu0a + gu0b, gu1 = gu1a + gu1b;
            #pragma unroll
            for (int r = 0; r < 4; ++r) {
                {
                    int s = s0 + lq * 4 + r;
                    float iv = sigmoidf_(gi0[r]), ov = sigmoidf_(go0[r]), uv = tanh_fast(gu0[r]);
                    float cc = iv * uv;
                    float hh = ov * tanh_fast(cc);
                    size_t o = ((size_t)b * SS + s) * HH + hc;
                    h0[o] = hh;
                    c0[o] = cc;
                }
                {
                    int s = s0 + 16 + lq * 4 + r;
                    float iv = sigmoidf_(gi1[r]), ov = sigmoidf_(go1[r]), uv = tanh_fast(gu1[r]);
                    float cc = iv * uv;
                    float hh = ov * tanh_fast(cc);
                    size_t o = ((size_t)b * SS + s) * HH + hc;
                    h0[o] = hh;
                    c0[o] = cc;
                }
            }
        }
    }
}

// ---------------- k_tree2: MFMA split-bf16 tree level (R5/R7 proven version) -------
__global__ __launch_bounds__(640) void k_tree2(
    const float* __restrict__ in_h, const float* __restrict__ in_c,
    float* __restrict__ out_h, float* __restrict__ out_c,
    int n_out,
    const ushort_t* __restrict__ utf, const float* __restrict__ bx)
{
    __shared__ ushort_t ahi[32 * AST], alo[32 * AST];

    const int b   = blockIdx.x;
    const int m0  = blockIdx.y * 32;
    const int tid = threadIdx.x;
    const int wv  = tid >> 6, lane = tid & 63;
    const int lc  = lane & 15, lq = lane >> 4;
    const int n_in = n_out * 2;

    const float* src = in_h + ((size_t)b * n_in + 2 * m0) * HH;
    for (int idx = tid; idx < 4800; idx += 640) {
        float2 v = *(const float2*)(src + idx * 2);
        int e = idx * 2;
        int r = e / 150, k = e - r * 150;
        int base = (r >> 1) * AST + (r & 1) * 160 + k;
        ushort_t ha, la, hb, lb;
        split_bf16(v.x, ha, la);
        split_bf16(v.y, hb, lb);
        ahi[base] = ha; ahi[base + 1] = hb;
        alo[base] = la; alo[base + 1] = lb;
    }
    {
        int m = tid / 20, j = tid - (tid / 20) * 20;
        int k = (j < 10) ? (150 + j) : (310 + j - 10);
        ahi[m * AST + k] = 0; alo[m * AST + k] = 0;
    }
    __syncthreads();

    const int hc = wv * 16 + lc;
    const bool hval = (hc < 150);
    const float bi = hval ? bx[hc] : 0.f;
    const float bl = hval ? bx[150 + hc] : 0.f;
    const float br = hval ? bx[300 + hc] : 0.f;
    const float bo = hval ? bx[450 + hc] : 0.f;
    const float bu = hval ? bx[600 + hc] : 0.f;
    f32x4 ai0 = {bi, bi, bi, bi}, ai1 = ai0;
    f32x4 al0 = {bl, bl, bl, bl}, al1 = al0;
    f32x4 ar0 = {br, br, br, br}, ar1 = ar0;
    f32x4 ao0 = {bo, bo, bo, bo}, ao1 = ao0;
    f32x4 au0 = {bu, bu, bu, bu}, au1 = au0;

    const size_t gstride = (size_t)100 * 1024;
    for (int kt = 0; kt < 10; ++kt) {
        int col = kt * 32 + (lq << 3);
        s16x8 A0h = *(const s16x8*)&ahi[lc * AST + col];
        s16x8 A0l = *(const s16x8*)&alo[lc * AST + col];
        s16x8 A1h = *(const s16x8*)&ahi[(lc + 16) * AST + col];
        s16x8 A1l = *(const s16x8*)&alo[(lc + 16) * AST + col];
        const ushort_t* pb = utf + ((size_t)(wv * 10 + kt) * 64 + lane) * 16;
        s16x8 Bh, Bl;
        Bh = *(const s16x8*)pb; Bl = *(const s16x8*)(pb + 8);
        ai0 = MFMA(A0h, Bh, ai0, 0, 0, 0); ai0 = MFMA(A0h, Bl, ai0, 0, 0, 0); ai0 = MFMA(A0l, Bh, ai0, 0, 0, 0);
        ai1 = MFMA(A1h, Bh, ai1, 0, 0, 0); ai1 = MFMA(A1h, Bl, ai1, 0, 0, 0); ai1 = MFMA(A1l, Bh, ai1, 0, 0, 0);
        pb += gstride;
        Bh = *(const s16x8*)pb; Bl = *(const s16x8*)(pb + 8);
        al0 = MFMA(A0h, Bh, al0, 0, 0, 0); al0 = MFMA(A0h, Bl, al0, 0, 0, 0); al0 = MFMA(A0l, Bh, al0, 0, 0, 0);
        al1 = MFMA(A1h, Bh, al1, 0, 0, 0); al1 = MFMA(A1h, Bl, al1, 0, 0, 0); al1 = MFMA(A1l, Bh, al1, 0, 0, 0);
        pb += gstride;
        Bh = *(const s16x8*)pb; Bl = *(const s16x8*)(pb + 8);
        ar0 = MFMA(A0h, Bh, ar0, 0, 0, 0); ar0 = MFMA(A0h, Bl, ar0, 0, 0, 0); ar0 = MFMA(A0l, Bh, ar0, 0, 0, 0);
        ar1 = MFMA(A1h, Bh, ar1, 0, 0, 0); ar1 = MFMA(A1h, Bl, ar1, 0, 0, 0); ar1 = MFMA(A1l, Bh, ar1, 0, 0, 0);
        pb += gstride;
        Bh = *(const s16x8*)pb; Bl = *(const s16x8*)(pb + 8);
        ao0 = MFMA(A0h, Bh, ao0, 0, 0, 0); ao0 = MFMA(A0h, Bl, ao0, 0, 0, 0); ao0 = MFMA(A0l, Bh, ao0, 0, 0, 0);
        ao1 = MFMA(A1h, Bh, ao1, 0, 0, 0); ao1 = MFMA(A1h, Bl, ao1, 0, 0, 0); ao1 = MFMA(A1l, Bh, ao1, 0, 0, 0);
        pb += gstride;
        Bh = *(const s16x8*)pb; Bl = *(const s16x8*)(pb + 8);
        au0 = MFMA(A0h, Bh, au0, 0, 0, 0); au0 = MFMA(A0h, Bl, au0, 0, 0, 0); au0 = MFMA(A0l, Bh, au0, 0, 0, 0);
        au1 = MFMA(A1h, Bh, au1, 0, 0, 0); au1 = MFMA(A1h, Bl, au1, 0, 0, 0); au1 = MFMA(A1l, Bh, au1, 0, 0, 0);
    }

    if (hval) {
        #pragma unroll
        for (int r = 0; r < 4; ++r) {
            int ml = lq * 4 + r;
            {
                int m = m0 + ml;
                size_t cb = ((size_t)b * n_in + 2 * m) * HH + hc;
                float iv = sigmoidf_(ai0[r]);
                float fl = sigmoidf_(al0[r]);
                float fr = sigmoidf_(ar0[r]);
                float ov = sigmoidf_(ao0[r]);
                float uv = tanh_fast(au0[r]);
                float cc = iv * uv + fl * in_c[cb] + fr * in_c[cb + HH];
                size_t ob = ((size_t)b * n_out + m) * HH + hc;
                out_h[ob] = ov * tanh_fast(cc);
                out_c[ob] = cc;
            }
            {
                int m = m0 + 16 + ml;
                size_t cb = ((size_t)b * n_in + 2 * m) * HH + hc;
                float iv = sigmoidf_(ai1[r]);
                float fl = sigmoidf_(al1[r]);
                float fr = sigmoidf_(ar1[r]);
                float ov = sigmoidf_(ao1[r]);
                float uv = tanh_fast(au1[r]);
                float cc = iv * uv + fl * in_c[cb] + fr * in_c[cb + HH];
                size_t ob = ((size_t)b * n_out + m) * HH + hc;
                out_h[ob] = ov * tanh_fast(cc);
                out_c[ob] = cc;
            }
        }
    }
}

// ---------------- k_tail: levels 16..1 in LDS + head MLP, 768 thr, 1 output/thread ----
template<int NN>
__device__ __forceinline__ void tail_level(
    const float* curh, const float* curc, float* nxth, float* nxtc, float* gs,
    const float* ul1, const float* ur1, float bx1, int o1, bool ov_, int tid)
{
    __syncthreads();
    if (ov_) {
        float a1[NN];
        #pragma unroll
        for (int m = 0; m < NN; ++m) a1[m] = bx1;
        for (int j = 0; j < 150; j += 2) {
            int r0 = j * UST, r1 = (j + 1) * UST;
            float wl1a = ul1[r0], wl1b = ul1[r1];
            float wr1a = ur1[r0], wr1b = ur1[r1];
            #pragma unroll
            for (int m = 0; m < NN; ++m) {
                float2 lv = *(const float2*)(curh + (2 * m) * LST + j);
                float2 rv = *(const float2*)(curh + (2 * m + 1) * LST + j);
                a1[m] += lv.x * wl1a + lv.y * wl1b + rv.x * wr1a + rv.y * wr1b;
            }
        }
        #pragma unroll
        for (int m = 0; m < NN; ++m) gs[m * GS + o1] = a1[m];
    }
    __syncthreads();
    for (int idx = tid; idx < NN * HH; idx += 768) {
        int m = idx / HH, h = idx - m * HH;
        float iv = sigmoidf_(gs[m * GS + h]);
        float fL = sigmoidf_(gs[m * GS + 150 + h]);
        float fR = sigmoidf_(gs[m * GS + 300 + h]);
        float ov = sigmoidf_(gs[m * GS + 450 + h]);
        float uv = tanh_fast(gs[m * GS + 600 + h]);
        float cc = iv * uv + fL * curc[2 * m * LST + h] + fR * curc[(2 * m + 1) * LST + h];
        nxth[m * LST + h] = ov * tanh_fast(cc);
        nxtc[m * LST + h] = cc;
    }
}

__global__ __launch_bounds__(768) void k_tail(
    const float* __restrict__ in_h, const float* __restrict__ in_c,
    const float* __restrict__ ULT, const float* __restrict__ URT,
    const float* __restrict__ bx,
    const float* __restrict__ W1, const float* __restrict__ b1,
    const float* __restrict__ W2, const float* __restrict__ b2,
    float* __restrict__ out)
{
    __shared__ float pool[96 * LST + TN * GS];
    float* Ah = pool;
    float* Ac = Ah + 32 * LST;
    float* Bh = Ac + 32 * LST;
    float* Bc = Bh + 16 * LST;
    float* gs = Bc + 16 * LST;
    __shared__ float z_s[80];

    const int b   = blockIdx.x;
    const int tid = threadIdx.x;

    for (int idx = tid; idx < 32 * HH; idx += 768) {
        int p = idx / HH, j = idx - p * HH;
        size_t base = ((size_t)b * 32 + p) * HH + j;
        Ah[p * LST + j] = in_h[base];
        Ac[p * LST + j] = in_c[base];
    }

    const int o1 = tid;
    const bool ov_ = (o1 < 750);
    const float bx1 = ov_ ? bx[o1] : 0.0f;
    const float* ul1 = ULT + (ov_ ? o1 : 0);
    const float* ur1 = URT + (ov_ ? o1 : 0);

    tail_level<16>(Ah, Ac, Bh, Bc, gs, ul1, ur1, bx1, o1, ov_, tid);
    tail_level<8 >(Bh, Bc, Ah, Ac, gs, ul1, ur1, bx1, o1, ov_, tid);
    tail_level<4 >(Ah, Ac, Bh, Bc, gs, ul1, ur1, bx1, o1, ov_, tid);
    tail_level<2 >(Bh, Bc, Ah, Ac, gs, ul1, ur1, bx1, o1, ov_, tid);
    tail_level<1 >(Ah, Ac, Bh, Bc, gs, ul1, ur1, bx1, o1, ov_, tid);
    __syncthreads();

    // head MLP on root = Bh row 0
    if (tid < 75) {
        const float* w = W1 + (size_t)tid * 150;
        float acc = b1[tid];
        for (int j = 0; j < 150; ++j) acc += Bh[j] * w[j];
        z_s[tid] = fmaxf(acc, 0.0f);
    }
    __syncthreads();
    if (tid < 3) {
        const float* w = W2 + (size_t)tid * 75;
        float acc = b2[tid];
        for (int j = 0; j < 75; ++j) acc += z_s[j] * w[j];
        out[(size_t)b * 3 + tid] = acc;
    }
}

extern "C" void kernel_launch(void* const* d_in, const int* in_sizes, int n_in,
                              void* d_out, int out_size, void* d_ws, size_t ws_size,
                              hipStream_t stream) {
    const int*   x   = (const int*)  d_in[0];
    const float* emb = (const float*)d_in[1];
    const float* w3  = (const float*)d_in[2];
    const float* b3  = (const float*)d_in[3];
    const float* w4  = (const float*)d_in[4];
    const float* b4  = (const float*)d_in[5];
    const float* w5  = (const float*)d_in[6];
    const float* b5  = (const float*)d_in[7];
    const float* Wp  = (const float*)d_in[8];
    const float* bp  = (const float*)d_in[9];
    const float* Wx  = (const float*)d_in[10];
    const float* bx  = (const float*)d_in[11];
    const float* UL  = (const float*)d_in[12];
    const float* UR  = (const float*)d_in[13];
    const float* W1  = (const float*)d_in[14];
    const float* b1  = (const float*)d_in[15];
    const float* W2  = (const float*)d_in[16];
    const float* b2  = (const float*)d_in[17];
    float* out = (float*)d_out;

    char* wsb = (char*)d_ws;
    const ushort_t* b1f = (const ushort_t*)(wsb + OB_B1);
    const ushort_t* b2f = (const ushort_t*)(wsb + OB_B2);
    const ushort_t* b3f = (const ushort_t*)(wsb + OB_B3);
    const ushort_t* utf = (const ushort_t*)(wsb + OB_UT);
    const float* bcat = (const float*)(wsb + OB_BC);
    const float* ULT  = (const float*)(wsb + OB_ULT);
    const float* URT  = (const float*)(wsb + OB_URT);
    float* h0 = (float*)(wsb + OB_H0);
    float* c0 = (float*)(wsb + OB_C0);
    float* h1 = (float*)(wsb + OB_H1);
    float* c1 = (float*)(wsb + OB_C1);

    {
        int total = 830 * 64 + 200 * 64 + 150 * 64 + 500 * 64 + 304 + 2 * 150 * UST;
        k_prep<<<(total + 255) / 256, 256, 0, stream>>>(
            w3, b3, w4, b4, w5, b5, Wp, Wx, UL, UR, wsb);
    }

    k_leaf<<<dim3(BB, SS / 32), 640, 0, stream>>>(
        x, emb, b1f, b2f, b3f, bcat, bp, bx, h0, c0);

    k_tree2<<<dim3(BB, 8), 640, 0, stream>>>(h0, c0, h1, c1, 256, utf, bx);
    k_tree2<<<dim3(BB, 4), 640, 0, stream>>>(h1, c1, h0, c0, 128, utf, bx);
    k_tree2<<<dim3(BB, 2), 640, 0, stream>>>(h0, c0, h1, c1,  64, utf, bx);
    k_tree2<<<dim3(BB, 1), 640, 0, stream>>>(h1, c1, h0, c0,  32, utf, bx);

    k_tail<<<BB, 768, 0, stream>>>(h0, c0, ULT, URT, bx, W1, b1, W2, b2, out);
}

// Round 11
// 569.641 us; speedup vs baseline: 1.3631x; 1.0565x over previous
//
#include <hip/hip_runtime.h>
#include <math.h>

#define BB 128
#define SS 512
#define EE 300
#define HH 150
#define TN 16
#define LST 152  // tail LDS row stride (floats)
#define GS 752   // tail gate buffer row stride
#define UST 752  // transposed UL/UR row stride (cols 750..751 zero)

// ---- workspace byte offsets ----
#define OB_B1   0u
#define OB_B2   1699840u
#define OB_B3   2109440u
#define OB_UT   2416640u
#define OB_BC   3440640u
#define OB_ULT  3442176u
#define OB_URT  3893376u
#define OB_H0   4344576u
#define SZB_HC0 39321600u
#define OB_C0   (OB_H0 + SZB_HC0)
#define OB_H1   (OB_C0 + SZB_HC0)
#define SZB_HC1 19660800u
#define OB_C1   (OB_H1 + SZB_HC1)

// LDS strides (ushorts)
#define EST 328
#define CST 328
#define LSU 168
#define AST 332

typedef short s16x8 __attribute__((ext_vector_type(8)));
typedef float f32x4 __attribute__((ext_vector_type(4)));
#define MFMA __builtin_amdgcn_mfma_f32_16x16x32_bf16

typedef unsigned short ushort_t;
typedef unsigned int uint_t;

__device__ __forceinline__ float sigmoidf_(float x) {
    return 1.0f / (1.0f + __expf(-x));
}
__device__ __forceinline__ float tanh_fast(float x) {
    x = fminf(fmaxf(x, -15.0f), 15.0f);
    float e = __expf(2.0f * x);
    return (e - 1.0f) / (e + 1.0f);
}
__device__ __forceinline__ ushort_t f2bf(float f) {
    uint_t u = __float_as_uint(f);
    return (ushort_t)((u + 0x7fffu + ((u >> 16) & 1u)) >> 16);
}
__device__ __forceinline__ void split_bf16(float f, ushort_t& hi, ushort_t& lo) {
    uint_t u = __float_as_uint(f);
    uint_t r = (u + 0x7fffu + ((u >> 16) & 1u)) >> 16;
    hi = (ushort_t)r;
    float d = f - __uint_as_float(r << 16);
    uint_t u2 = __float_as_uint(d);
    uint_t r2 = (u2 + 0x7fffu + ((u2 >> 16) & 1u)) >> 16;
    lo = (ushort_t)r2;
}

__device__ __forceinline__ int b1_tile(int nt, int kt) {
    return (nt < 12) ? nt * 40 + (kt - 10) : 480 + (nt - 12) * 50 + kt;
}

__device__ __forceinline__ void pack_frag(uint_t* out, const ushort_t* hv, const ushort_t* lv) {
    out[0] = hv[0] | (hv[1] << 16); out[1] = hv[2] | (hv[3] << 16);
    out[2] = hv[4] | (hv[5] << 16); out[3] = hv[6] | (hv[7] << 16);
    out[4] = lv[0] | (lv[1] << 16); out[5] = lv[2] | (lv[3] << 16);
    out[6] = lv[4] | (lv[5] << 16); out[7] = lv[6] | (lv[7] << 16);
}

// ---------------- k_prep (unchanged) ----------------
__global__ __launch_bounds__(256) void k_prep(
    const float* __restrict__ w3, const float* __restrict__ b3,
    const float* __restrict__ w4, const float* __restrict__ b4,
    const float* __restrict__ w5, const float* __restrict__ b5,
    const float* __restrict__ Wp, const float* __restrict__ Wx,
    const float* __restrict__ UL, const float* __restrict__ UR,
    char* __restrict__ wsb)
{
    const int W1 = 830 * 64, W2 = 200 * 64, W3 = 150 * 64, WU = 500 * 64;
    int i = blockIdx.x * 256 + threadIdx.x;
    if (i < W1) {
        int T = i >> 6, lane = i & 63;
        int nt, kt;
        if (T < 480) { nt = T / 40; kt = T % 40 + 10; }
        else { int T2 = T - 480; nt = 12 + T2 / 50; kt = T2 % 50; }
        int t = kt / 10, jjb = (kt - t * 10) * 32 + ((lane >> 4) << 3);
        int f = nt * 16 + (lane & 15);
        ushort_t hv[8], lv[8];
        #pragma unroll
        for (int e = 0; e < 8; ++e) {
            int jj = jjb + e;
            float w = 0.0f;
            if (f < 300 && jj < 300) {
                if (f < 100)      { if (t >= 1 && t <= 3) w = w3[f * 900 + jj * 3 + (t - 1)]; }
                else if (f < 200) { if (t >= 1)           w = w4[(f - 100) * 1200 + jj * 4 + (t - 1)]; }
                else              {                       w = w5[(f - 200) * 1500 + jj * 5 + t]; }
            }
            split_bf16(w, hv[e], lv[e]);
        }
        pack_frag((uint_t*)(wsb + OB_B1 + ((size_t)T * 64 + lane) * 32), hv, lv);
        return;
    }
    i -= W1;
    if (i < W2) {
        int T = i >> 6, lane = i & 63;
        int nt = T / 20, kt = T % 20;
        int h = nt * 16 + (lane & 15);
        int kb = kt * 32 + ((lane >> 4) << 3);
        ushort_t hv[8], lv[8];
        #pragma unroll
        for (int e = 0; e < 8; ++e) {
            int k = kb + e;
            float w = 0.0f;
            if (h < 150) {
                if (kt < 10) { if (k < 300) w = Wp[h * 600 + k]; }
                else { int k2 = k - 320; if (k2 < 300) w = Wp[h * 600 + 300 + k2]; }
            }
            split_bf16(w, hv[e], lv[e]);
        }
        pack_frag((uint_t*)(wsb + OB_B2 + ((size_t)T * 64 + lane) * 32), hv, lv);
        return;
    }
    i -= W2;
    if (i < W3) {
        int T = i >> 6, lane = i & 63;
        int nt3 = T / 5, kt = T % 5;
        int g = nt3 / 10, h16 = nt3 % 10;
        int h = h16 * 16 + (lane & 15);
        int kb = kt * 32 + ((lane >> 4) << 3);
        int row = (g == 0 ? 0 : (g == 1 ? 450 : 600)) + h;
        ushort_t hv[8], lv[8];
        #pragma unroll
        for (int e = 0; e < 8; ++e) {
            int k = kb + e;
            float w = (h < 150 && k < 150) ? Wx[row * 150 + k] : 0.0f;
            split_bf16(w, hv[e], lv[e]);
        }
        pack_frag((uint_t*)(wsb + OB_B3 + ((size_t)T * 64 + lane) * 32), hv, lv);
        return;
    }
    i -= W3;
    if (i < WU) {
        int T = i >> 6, lane = i & 63;
        int g = T / 100, rem = T - g * 100;
        int ht = rem / 10, kt = rem - ht * 10;
        int h = ht * 16 + (lane & 15);
        int kb = kt * 32 + ((lane >> 4) << 3);
        ushort_t hv[8], lv[8];
        #pragma unroll
        for (int e = 0; e < 8; ++e) {
            int k = kb + e;
            int half = (k >= 160);
            int j = k - half * 160;
            float w = 0.0f;
            if (h < 150 && j < 150) {
                const float* U = half ? UR : UL;
                w = U[(g * 150 + h) * 150 + j];
            }
            split_bf16(w, hv[e], lv[e]);
        }
        pack_frag((uint_t*)(wsb + OB_UT + ((size_t)T * 64 + lane) * 32), hv, lv);
        return;
    }
    i -= WU;
    if (i < 304) {
        float v = (i < 100) ? b3[i] : (i < 200 ? b4[i - 100] : (i < 300 ? b5[i - 200] : 0.0f));
        ((float*)(wsb + OB_BC))[i] = v;
        return;
    }
    i -= 304;
    if (i < 150 * UST) {
        int j = i / UST, o = i - j * UST;
        ((float*)(wsb + OB_ULT))[i] = (o < 750) ? UL[o * 150 + j] : 0.0f;
        return;
    }
    i -= 150 * UST;
    if (i < 150 * UST) {
        int j = i / UST, o = i - j * UST;
        ((float*)(wsb + OB_URT))[i] = (o < 750) ? UR[o * 150 + j] : 0.0f;
        return;
    }
}

// A-fragment loader (phase 1), hi only
#define LDA(kt_, d0h, d1h) { \
    int t_ = (kt_) / 10; \
    int jj_ = ((kt_) - t_ * 10) * 32 + (lq << 3); \
    int ra_ = lc + t_; \
    d0h = *(const s16x8*)&ehi[ra_ * EST + jj_]; \
    d1h = *(const s16x8*)&ehi[(ra_ + 16) * EST + jj_]; }

// ---------------- k_leaf: A = plain bf16, B = split hi/lo (2 MFMA/product), 54KB LDS ----
__global__ __launch_bounds__(640) void k_leaf(
    const int* __restrict__ x, const float* __restrict__ emb,
    const ushort_t* __restrict__ b1f, const ushort_t* __restrict__ b2f,
    const ushort_t* __restrict__ b3f, const float* __restrict__ bcat,
    const float* __restrict__ bp, const float* __restrict__ bx,
    float* __restrict__ h0, float* __restrict__ c0)
{
    __shared__ ushort_t ehi[36 * EST];
    __shared__ ushort_t chi[32 * CST];
    __shared__ ushort_t lhi[32 * LSU];

    const int b   = blockIdx.x;
    const int s0  = blockIdx.y * 32;
    const int tid = threadIdx.x;
    const int wv  = tid >> 6;
    const int lane = tid & 63;
    const int lc = lane & 15, lq = lane >> 4;

    // ---- phase 0: gather e rows (36 x 300), round to bf16 ----
    for (int idx = tid; idx < 36 * 75; idx += 640) {
        int r = idx / 75, q = idx - r * 75;
        int sp = s0 - 2 + r;
        float4 v = make_float4(0.f, 0.f, 0.f, 0.f);
        if (sp >= 0 && sp < SS) {
            int tok = x[b * SS + sp];
            v = *reinterpret_cast<const float4*>(emb + (size_t)tok * EE + q * 4);
        }
        *(ushort4*)&ehi[r * EST + q * 4] =
            make_ushort4(f2bf(v.x), f2bf(v.y), f2bf(v.z), f2bf(v.w));
    }
    for (int idx = tid; idx < 36 * 20; idx += 640) {
        int r = idx / 20, c = 300 + idx % 20;
        ehi[r * EST + c] = 0;
    }
    for (int idx = tid; idx < 32 * 16; idx += 640) {
        int r = idx / 16, c = 304 + idx % 16;
        chi[r * CST + c] = 0;
    }
    __syncthreads();

    // ---- phase 1: conv GEMM, 2-slot A+B register pipeline, 8 MFMA/kt ----
    {
        const int nt0 = wv;
        const int nt1 = (wv == 9) ? 18 : wv + 10;
        const bool st1 = (wv < 9);
        const int f0 = nt0 * 16 + lc;
        const int f1 = nt1 * 16 + lc;
        const float bv0 = bcat[f0];
        const float bv1 = st1 ? bcat[f1] : 0.0f;
        const f32x4 z4 = {0.f, 0.f, 0.f, 0.f};
        f32x4 s00a = {bv0, bv0, bv0, bv0}, s00b = z4;
        f32x4 s01a = s00a,                 s01b = z4;
        f32x4 s10a = {bv1, bv1, bv1, bv1}, s10b = z4;
        f32x4 s11a = s10a,                 s11b = z4;

        if (nt1 >= 12) {
            #pragma unroll
            for (int kt = 0; kt < 10; ++kt) {
                const ushort_t* p8 = b1f + ((size_t)b1_tile(nt1, kt) * 64 + lane) * 16;
                s16x8 Bh = *(const s16x8*)p8;
                s16x8 Bl = *(const s16x8*)(p8 + 8);
                int jj = kt * 32 + (lq << 3);
                s16x8 A0h = *(const s16x8*)&ehi[lc * EST + jj];
                s16x8 A1h = *(const s16x8*)&ehi[(lc + 16) * EST + jj];
                s10a = MFMA(A0h, Bh, s10a, 0, 0, 0);
                s10b = MFMA(A0h, Bl, s10b, 0, 0, 0);
                s11a = MFMA(A1h, Bh, s11a, 0, 0, 0);
                s11b = MFMA(A1h, Bl, s11b, 0, 0, 0);
            }
        }

        // prime B (2 deep) and A (2 deep)
        const ushort_t* p;
        p = b1f + ((size_t)b1_tile(nt0, 10) * 64 + lane) * 16;
        s16x8 Bha0 = *(const s16x8*)p, Bla0 = *(const s16x8*)(p + 8);
        p = b1f + ((size_t)b1_tile(nt1, 10) * 64 + lane) * 16;
        s16x8 Bha1 = *(const s16x8*)p, Bla1 = *(const s16x8*)(p + 8);
        p = b1f + ((size_t)b1_tile(nt0, 11) * 64 + lane) * 16;
        s16x8 Bhb0 = *(const s16x8*)p, Blb0 = *(const s16x8*)(p + 8);
        p = b1f + ((size_t)b1_tile(nt1, 11) * 64 + lane) * 16;
        s16x8 Bhb1 = *(const s16x8*)p, Blb1 = *(const s16x8*)(p + 8);

        s16x8 Pa0h, Pa1h, Pb0h, Pb1h;
        LDA(10, Pa0h, Pa1h);
        LDA(11, Pb0h, Pb1h);

        for (int kt = 10; kt < 50; kt += 2) {
            int k2 = (kt + 2 < 50) ? kt + 2 : 10;
            p = b1f + ((size_t)b1_tile(nt0, k2) * 64 + lane) * 16;
            s16x8 nha0 = *(const s16x8*)p, nla0 = *(const s16x8*)(p + 8);
            p = b1f + ((size_t)b1_tile(nt1, k2) * 64 + lane) * 16;
            s16x8 nha1 = *(const s16x8*)p, nla1 = *(const s16x8*)(p + 8);

            // compute kt with pre-loaded A (Pa*)
            s00a = MFMA(Pa0h, Bha0, s00a, 0, 0, 0);
            s00b = MFMA(Pa0h, Bla0, s00b, 0, 0, 0);
            s01a = MFMA(Pa1h, Bha0, s01a, 0, 0, 0);
            s01b = MFMA(Pa1h, Bla0, s01b, 0, 0, 0);
            s10a = MFMA(Pa0h, Bha1, s10a, 0, 0, 0);
            s10b = MFMA(Pa0h, Bla1, s10b, 0, 0, 0);
            s11a = MFMA(Pa1h, Bha1, s11a, 0, 0, 0);
            s11b = MFMA(Pa1h, Bla1, s11b, 0, 0, 0);

            LDA(k2, Pa0h, Pa1h);

            int k3 = (kt + 3 < 50) ? kt + 3 : 11;
            p = b1f + ((size_t)b1_tile(nt0, k3) * 64 + lane) * 16;
            s16x8 nhb0 = *(const s16x8*)p, nlb0 = *(const s16x8*)(p + 8);
            p = b1f + ((size_t)b1_tile(nt1, k3) * 64 + lane) * 16;
            s16x8 nhb1 = *(const s16x8*)p, nlb1 = *(const s16x8*)(p + 8);

            // compute kt+1 with pre-loaded A (Pb*)
            s00a = MFMA(Pb0h, Bhb0, s00a, 0, 0, 0);
            s00b = MFMA(Pb0h, Blb0, s00b, 0, 0, 0);
            s01a = MFMA(Pb1h, Bhb0, s01a, 0, 0, 0);
            s01b = MFMA(Pb1h, Blb0, s01b, 0, 0, 0);
            s10a = MFMA(Pb0h, Bhb1, s10a, 0, 0, 0);
            s10b = MFMA(Pb0h, Blb1, s10b, 0, 0, 0);
            s11a = MFMA(Pb1h, Bhb1, s11a, 0, 0, 0);
            s11b = MFMA(Pb1h, Blb1, s11b, 0, 0, 0);

            LDA(k3, Pb0h, Pb1h);

            Bha0 = nha0; Bla0 = nla0; Bha1 = nha1; Bla1 = nla1;
            Bhb0 = nhb0; Blb0 = nlb0; Bhb1 = nhb1; Blb1 = nlb1;
        }

        f32x4 c00 = s00a + s00b;
        f32x4 c01 = s01a + s01b;
        f32x4 c10 = s10a + s10b;
        f32x4 c11 = s11a + s11b;

        #pragma unroll
        for (int r = 0; r < 4; ++r) {
            int pp = lq * 4 + r;
            chi[pp * CST + f0]        = f2bf(fmaxf(c00[r], 0.0f));
            chi[(pp + 16) * CST + f0] = f2bf(fmaxf(c01[r], 0.0f));
            if (st1) {
                chi[pp * CST + f1]        = f2bf(fmaxf(c10[r], 0.0f));
                chi[(pp + 16) * CST + f1] = f2bf(fmaxf(c11[r], 0.0f));
            }
        }
    }
    __syncthreads();

    // ---- phase 2: leaf projection GEMM (4 MFMA/kt) ----
    {
        const int hcol = wv * 16 + lc;
        const float bv = (hcol < 150) ? bp[hcol] : 0.0f;
        const f32x4 z4 = {0.f, 0.f, 0.f, 0.f};
        f32x4 d0a = {bv, bv, bv, bv}, d0b = z4;
        f32x4 d1a = d0a,              d1b = z4;
        #pragma unroll
        for (int kt = 0; kt < 20; ++kt) {
            s16x8 A0h, A1h;
            if (kt < 10) {
                int col = kt * 32 + (lq << 3);
                int ra = lc + 2;
                A0h = *(const s16x8*)&ehi[ra * EST + col];
                A1h = *(const s16x8*)&ehi[(ra + 16) * EST + col];
            } else {
                int col = (kt - 10) * 32 + (lq << 3);
                A0h = *(const s16x8*)&chi[lc * CST + col];
                A1h = *(const s16x8*)&chi[(lc + 16) * CST + col];
            }
            const ushort_t* p8 = b2f + ((size_t)(wv * 20 + kt) * 64 + lane) * 16;
            s16x8 Bh = *(const s16x8*)p8;
            s16x8 Bl = *(const s16x8*)(p8 + 8);
            d0a = MFMA(A0h, Bh, d0a, 0, 0, 0);
            d0b = MFMA(A0h, Bl, d0b, 0, 0, 0);
            d1a = MFMA(A1h, Bh, d1a, 0, 0, 0);
            d1b = MFMA(A1h, Bl, d1b, 0, 0, 0);
        }
        f32x4 d0 = d0a + d0b;
        f32x4 d1 = d1a + d1b;
        #pragma unroll
        for (int r = 0; r < 4; ++r) {
            int pp = lq * 4 + r;
            lhi[pp * LSU + hcol]        = f2bf(d0[r]);
            lhi[(pp + 16) * LSU + hcol] = f2bf(d1[r]);
        }
    }
    __syncthreads();

    // ---- phase 3: leaf gates (i,o,u) GEMM + cell (12 MFMA/kt) ----
    {
        const int hc = wv * 16 + lc;
        const bool hval = (hc < 150);
        const float bi = hval ? bx[hc] : 0.0f;
        const float bo = hval ? bx[450 + hc] : 0.0f;
        const float bu = hval ? bx[600 + hc] : 0.0f;
        const f32x4 z4 = {0.f, 0.f, 0.f, 0.f};
        f32x4 gi0a = {bi, bi, bi, bi}, gi0b = z4, gi1a = gi0a, gi1b = z4;
        f32x4 go0a = {bo, bo, bo, bo}, go0b = z4, go1a = go0a, go1b = z4;
        f32x4 gu0a = {bu, bu, bu, bu}, gu0b = z4, gu1a = gu0a, gu1b = z4;
        #pragma unroll
        for (int kt = 0; kt < 5; ++kt) {
            int col = kt * 32 + (lq << 3);
            s16x8 A0h = *(const s16x8*)&lhi[lc * LSU + col];
            s16x8 A1h = *(const s16x8*)&lhi[(lc + 16) * LSU + col];
            const ushort_t* p8i = b3f + ((size_t)((0 + wv) * 5 + kt) * 64 + lane) * 16;
            const ushort_t* p8o = b3f + ((size_t)((10 + wv) * 5 + kt) * 64 + lane) * 16;
            const ushort_t* p8u = b3f + ((size_t)((20 + wv) * 5 + kt) * 64 + lane) * 16;
            s16x8 Bh, Bl;
            Bh = *(const s16x8*)p8i; Bl = *(const s16x8*)(p8i + 8);
            gi0a = MFMA(A0h, Bh, gi0a, 0, 0, 0); gi0b = MFMA(A0h, Bl, gi0b, 0, 0, 0);
            gi1a = MFMA(A1h, Bh, gi1a, 0, 0, 0); gi1b = MFMA(A1h, Bl, gi1b, 0, 0, 0);
            Bh = *(const s16x8*)p8o; Bl = *(const s16x8*)(p8o + 8);
            go0a = MFMA(A0h, Bh, go0a, 0, 0, 0); go0b = MFMA(A0h, Bl, go0b, 0, 0, 0);
            go1a = MFMA(A1h, Bh, go1a, 0, 0, 0); go1b = MFMA(A1h, Bl, go1b, 0, 0, 0);
            Bh = *(const s16x8*)p8u; Bl = *(const s16x8*)(p8u + 8);
            gu0a = MFMA(A0h, Bh, gu0a, 0, 0, 0); gu0b = MFMA(A0h, Bl, gu0b, 0, 0, 0);
            gu1a = MFMA(A1h, Bh, gu1a, 0, 0, 0); gu1b = MFMA(A1h, Bl, gu1b, 0, 0, 0);
        }
        if (hval) {
            f32x4 gi0 = gi0a + gi0b, gi1 = gi1a + gi1b;
            f32x4 go0 = go0a + go0b, go1 = go1a + go1b;
            f32x4 gu0 = gu0a + gu0b, gu1 = gu1a + gu1b;
            #pragma unroll
            for (int r = 0; r < 4; ++r) {
                {
                    int s = s0 + lq * 4 + r;
                    float iv = sigmoidf_(gi0[r]), ov = sigmoidf_(go0[r]), uv = tanh_fast(gu0[r]);
                    float cc = iv * uv;
                    float hh = ov * tanh_fast(cc);
                    size_t o = ((size_t)b * SS + s) * HH + hc;
                    h0[o] = hh;
                    c0[o] = cc;
                }
                {
                    int s = s0 + 16 + lq * 4 + r;
                    float iv = sigmoidf_(gi1[r]), ov = sigmoidf_(go1[r]), uv = tanh_fast(gu1[r]);
                    float cc = iv * uv;
                    float hh = ov * tanh_fast(cc);
                    size_t o = ((size_t)b * SS + s) * HH + hc;
                    h0[o] = hh;
                    c0[o] = cc;
                }
            }
        }
    }
}

// ---------------- k_tree2: MFMA split-bf16 tree level (proven, unchanged) -------
__global__ __launch_bounds__(640) void k_tree2(
    const float* __restrict__ in_h, const float* __restrict__ in_c,
    float* __restrict__ out_h, float* __restrict__ out_c,
    int n_out,
    const ushort_t* __restrict__ utf, const float* __restrict__ bx)
{
    __shared__ ushort_t ahi[32 * AST], alo[32 * AST];

    const int b   = blockIdx.x;
    const int m0  = blockIdx.y * 32;
    const int tid = threadIdx.x;
    const int wv  = tid >> 6, lane = tid & 63;
    const int lc  = lane & 15, lq = lane >> 4;
    const int n_in = n_out * 2;

    const float* src = in_h + ((size_t)b * n_in + 2 * m0) * HH;
    for (int idx = tid; idx < 4800; idx += 640) {
        float2 v = *(const float2*)(src + idx * 2);
        int e = idx * 2;
        int r = e / 150, k = e - r * 150;
        int base = (r >> 1) * AST + (r & 1) * 160 + k;
        ushort_t ha, la, hb, lb;
        split_bf16(v.x, ha, la);
        split_bf16(v.y, hb, lb);
        ahi[base] = ha; ahi[base + 1] = hb;
        alo[base] = la; alo[base + 1] = lb;
    }
    {
        int m = tid / 20, j = tid - (tid / 20) * 20;
        int k = (j < 10) ? (150 + j) : (310 + j - 10);
        ahi[m * AST + k] = 0; alo[m * AST + k] = 0;
    }
    __syncthreads();

    const int hc = wv * 16 + lc;
    const bool hval = (hc < 150);
    const float bi = hval ? bx[hc] : 0.f;
    const float bl = hval ? bx[150 + hc] : 0.f;
    const float br = hval ? bx[300 + hc] : 0.f;
    const float bo = hval ? bx[450 + hc] : 0.f;
    const float bu = hval ? bx[600 + hc] : 0.f;
    f32x4 ai0 = {bi, bi, bi, bi}, ai1 = ai0;
    f32x4 al0 = {bl, bl, bl, bl}, al1 = al0;
    f32x4 ar0 = {br, br, br, br}, ar1 = ar0;
    f32x4 ao0 = {bo, bo, bo, bo}, ao1 = ao0;
    f32x4 au0 = {bu, bu, bu, bu}, au1 = au0;

    const size_t gstride = (size_t)100 * 1024;
    for (int kt = 0; kt < 10; ++kt) {
        int col = kt * 32 + (lq << 3);
        s16x8 A0h = *(const s16x8*)&ahi[lc * AST + col];
        s16x8 A0l = *(const s16x8*)&alo[lc * AST + col];
        s16x8 A1h = *(const s16x8*)&ahi[(lc + 16) * AST + col];
        s16x8 A1l = *(const s16x8*)&alo[(lc + 16) * AST + col];
        const ushort_t* pb = utf + ((size_t)(wv * 10 + kt) * 64 + lane) * 16;
        s16x8 Bh, Bl;
        Bh = *(const s16x8*)pb; Bl = *(const s16x8*)(pb + 8);
        ai0 = MFMA(A0h, Bh, ai0, 0, 0, 0); ai0 = MFMA(A0h, Bl, ai0, 0, 0, 0); ai0 = MFMA(A0l, Bh, ai0, 0, 0, 0);
        ai1 = MFMA(A1h, Bh, ai1, 0, 0, 0); ai1 = MFMA(A1h, Bl, ai1, 0, 0, 0); ai1 = MFMA(A1l, Bh, ai1, 0, 0, 0);
        pb += gstride;
        Bh = *(const s16x8*)pb; Bl = *(const s16x8*)(pb + 8);
        al0 = MFMA(A0h, Bh, al0, 0, 0, 0); al0 = MFMA(A0h, Bl, al0, 0, 0, 0); al0 = MFMA(A0l, Bh, al0, 0, 0, 0);
        al1 = MFMA(A1h, Bh, al1, 0, 0, 0); al1 = MFMA(A1h, Bl, al1, 0, 0, 0); al1 = MFMA(A1l, Bh, al1, 0, 0, 0);
        pb += gstride;
        Bh = *(const s16x8*)pb; Bl = *(const s16x8*)(pb + 8);
        ar0 = MFMA(A0h, Bh, ar0, 0, 0, 0); ar0 = MFMA(A0h, Bl, ar0, 0, 0, 0); ar0 = MFMA(A0l, Bh, ar0, 0, 0, 0);
        ar1 = MFMA(A1h, Bh, ar1, 0, 0, 0); ar1 = MFMA(A1h, Bl, ar1, 0, 0, 0); ar1 = MFMA(A1l, Bh, ar1, 0, 0, 0);
        pb += gstride;
        Bh = *(const s16x8*)pb; Bl = *(const s16x8*)(pb + 8);
        ao0 = MFMA(A0h, Bh, ao0, 0, 0, 0); ao0 = MFMA(A0h, Bl, ao0, 0, 0, 0); ao0 = MFMA(A0l, Bh, ao0, 0, 0, 0);
        ao1 = MFMA(A1h, Bh, ao1, 0, 0, 0); ao1 = MFMA(A1h, Bl, ao1, 0, 0, 0); ao1 = MFMA(A1l, Bh, ao1, 0, 0, 0);
        pb += gstride;
        Bh = *(const s16x8*)pb; Bl = *(const s16x8*)(pb + 8);
        au0 = MFMA(A0h, Bh, au0, 0, 0, 0); au0 = MFMA(A0h, Bl, au0, 0, 0, 0); au0 = MFMA(A0l, Bh, au0, 0, 0, 0);
        au1 = MFMA(A1h, Bh, au1, 0, 0, 0); au1 = MFMA(A1h, Bl, au1, 0, 0, 0); au1 = MFMA(A1l, Bh, au1, 0, 0, 0);
    }

    if (hval) {
        #pragma unroll
        for (int r = 0; r < 4; ++r) {
            int ml = lq * 4 + r;
            {
                int m = m0 + ml;
                size_t cb = ((size_t)b * n_in + 2 * m) * HH + hc;
                float iv = sigmoidf_(ai0[r]);
                float fl = sigmoidf_(al0[r]);
                float fr = sigmoidf_(ar0[r]);
                float ov = sigmoidf_(ao0[r]);
                float uv = tanh_fast(au0[r]);
                float cc = iv * uv + fl * in_c[cb] + fr * in_c[cb + HH];
                size_t ob = ((size_t)b * n_out + m) * HH + hc;
                out_h[ob] = ov * tanh_fast(cc);
                out_c[ob] = cc;
            }
            {
                int m = m0 + 16 + ml;
                size_t cb = ((size_t)b * n_in + 2 * m) * HH + hc;
                float iv = sigmoidf_(ai1[r]);
                float fl = sigmoidf_(al1[r]);
                float fr = sigmoidf_(ar1[r]);
                float ov = sigmoidf_(ao1[r]);
                float uv = tanh_fast(au1[r]);
                float cc = iv * uv + fl * in_c[cb] + fr * in_c[cb + HH];
                size_t ob = ((size_t)b * n_out + m) * HH + hc;
                out_h[ob] = ov * tanh_fast(cc);
                out_c[ob] = cc;
            }
        }
    }
}

// ---------------- k_tail: levels 16..1 in LDS + head MLP, 768 thr (R10 version) ----
template<int NN>
__device__ __forceinline__ void tail_level(
    const float* curh, const float* curc, float* nxth, float* nxtc, float* gs,
    const float* ul1, const float* ur1, float bx1, int o1, bool ov_, int tid)
{
    __syncthreads();
    if (ov_) {
        float a1[NN];
        #pragma unroll
        for (int m = 0; m < NN; ++m) a1[m] = bx1;
        for (int j = 0; j < 150; j += 2) {
            int r0 = j * UST, r1 = (j + 1) * UST;
            float wl1a = ul1[r0], wl1b = ul1[r1];
            float wr1a = ur1[r0], wr1b = ur1[r1];
            #pragma unroll
            for (int m = 0; m < NN; ++m) {
                float2 lv = *(const float2*)(curh + (2 * m) * LST + j);
                float2 rv = *(const float2*)(curh + (2 * m + 1) * LST + j);
                a1[m] += lv.x * wl1a + lv.y * wl1b + rv.x * wr1a + rv.y * wr1b;
            }
        }
        #pragma unroll
        for (int m = 0; m < NN; ++m) gs[m * GS + o1] = a1[m];
    }
    __syncthreads();
    for (int idx = tid; idx < NN * HH; idx += 768) {
        int m = idx / HH, h = idx - m * HH;
        float iv = sigmoidf_(gs[m * GS + h]);
        float fL = sigmoidf_(gs[m * GS + 150 + h]);
        float fR = sigmoidf_(gs[m * GS + 300 + h]);
        float ov = sigmoidf_(gs[m * GS + 450 + h]);
        float uv = tanh_fast(gs[m * GS + 600 + h]);
        float cc = iv * uv + fL * curc[2 * m * LST + h] + fR * curc[(2 * m + 1) * LST + h];
        nxth[m * LST + h] = ov * tanh_fast(cc);
        nxtc[m * LST + h] = cc;
    }
}

__global__ __launch_bounds__(768) void k_tail(
    const float* __restrict__ in_h, const float* __restrict__ in_c,
    const float* __restrict__ ULT, const float* __restrict__ URT,
    const float* __restrict__ bx,
    const float* __restrict__ W1, const float* __restrict__ b1,
    const float* __restrict__ W2, const float* __restrict__ b2,
    float* __restrict__ out)
{
    __shared__ float pool[96 * LST + TN * GS];
    float* Ah = pool;
    float* Ac = Ah + 32 * LST;
    float* Bh = Ac + 32 * LST;
    float* Bc = Bh + 16 * LST;
    float* gs = Bc + 16 * LST;
    __shared__ float z_s[80];

    const int b   = blockIdx.x;
    const int tid = threadIdx.x;

    for (int idx = tid; idx < 32 * HH; idx += 768) {
        int p = idx / HH, j = idx - p * HH;
        size_t base = ((size_t)b * 32 + p) * HH + j;
        Ah[p * LST + j] = in_h[base];
        Ac[p * LST + j] = in_c[base];
    }

    const int o1 = tid;
    const bool ov_ = (o1 < 750);
    const float bx1 = ov_ ? bx[o1] : 0.0f;
    const float* ul1 = ULT + (ov_ ? o1 : 0);
    const float* ur1 = URT + (ov_ ? o1 : 0);

    tail_level<16>(Ah, Ac, Bh, Bc, gs, ul1, ur1, bx1, o1, ov_, tid);
    tail_level<8 >(Bh, Bc, Ah, Ac, gs, ul1, ur1, bx1, o1, ov_, tid);
    tail_level<4 >(Ah, Ac, Bh, Bc, gs, ul1, ur1, bx1, o1, ov_, tid);
    tail_level<2 >(Bh, Bc, Ah, Ac, gs, ul1, ur1, bx1, o1, ov_, tid);
    tail_level<1 >(Ah, Ac, Bh, Bc, gs, ul1, ur1, bx1, o1, ov_, tid);
    __syncthreads();

    if (tid < 75) {
        const float* w = W1 + (size_t)tid * 150;
        float acc = b1[tid];
        for (int j = 0; j < 150; ++j) acc += Bh[j] * w[j];
        z_s[tid] = fmaxf(acc, 0.0f);
    }
    __syncthreads();
    if (tid < 3) {
        const float* w = W2 + (size_t)tid * 75;
        float acc = b2[tid];
        for (int j = 0; j < 75; ++j) acc += z_s[j] * w[j];
        out[(size_t)b * 3 + tid] = acc;
    }
}

extern "C" void kernel_launch(void* const* d_in, const int* in_sizes, int n_in,
                              void* d_out, int out_size, void* d_ws, size_t ws_size,
                              hipStream_t stream) {
    const int*   x   = (const int*)  d_in[0];
    const float* emb = (const float*)d_in[1];
    const float* w3  = (const float*)d_in[2];
    const float* b3  = (const float*)d_in[3];
    const float* w4  = (const float*)d_in[4];
    const float* b4  = (const float*)d_in[5];
    const float* w5  = (const float*)d_in[6];
    const float* b5  = (const float*)d_in[7];
    const float* Wp  = (const float*)d_in[8];
    const float* bp  = (const float*)d_in[9];
    const float* Wx  = (const float*)d_in[10];
    const float* bx  = (const float*)d_in[11];
    const float* UL  = (const float*)d_in[12];
    const float* UR  = (const float*)d_in[13];
    const float* W1  = (const float*)d_in[14];
    const float* b1  = (const float*)d_in[15];
    const float* W2  = (const float*)d_in[16];
    const float* b2  = (const float*)d_in[17];
    float* out = (float*)d_out;

    char* wsb = (char*)d_ws;
    const ushort_t* b1f = (const ushort_t*)(wsb + OB_B1);
    const ushort_t* b2f = (const ushort_t*)(wsb + OB_B2);
    const ushort_t* b3f = (const ushort_t*)(wsb + OB_B3);
    const ushort_t* utf = (const ushort_t*)(wsb + OB_UT);
    const float* bcat = (const float*)(wsb + OB_BC);
    const float* ULT  = (const float*)(wsb + OB_ULT);
    const float* URT  = (const float*)(wsb + OB_URT);
    float* h0 = (float*)(wsb + OB_H0);
    float* c0 = (float*)(wsb + OB_C0);
    float* h1 = (float*)(wsb + OB_H1);
    float* c1 = (float*)(wsb + OB_C1);

    {
        int total = 830 * 64 + 200 * 64 + 150 * 64 + 500 * 64 + 304 + 2 * 150 * UST;
        k_prep<<<(total + 255) / 256, 256, 0, stream>>>(
            w3, b3, w4, b4, w5, b5, Wp, Wx, UL, UR, wsb);
    }

    k_leaf<<<dim3(BB, SS / 32), 640, 0, stream>>>(
        x, emb, b1f, b2f, b3f, bcat, bp, bx, h0, c0);

    k_tree2<<<dim3(BB, 8), 640, 0, stream>>>(h0, c0, h1, c1, 256, utf, bx);
    k_tree2<<<dim3(BB, 4), 640, 0, stream>>>(h1, c1, h0, c0, 128, utf, bx);
    k_tree2<<<dim3(BB, 2), 640, 0, stream>>>(h0, c0, h1, c1,  64, utf, bx);
    k_tree2<<<dim3(BB, 1), 640, 0, stream>>>(h1, c1, h0, c0,  32, utf, bx);

    k_tail<<<BB, 768, 0, stream>>>(h0, c0, ULT, URT, bx, W1, b1, W2, b2, out);
}